// Round 15
// baseline (637.607 us; speedup 1.0000x reference)
//
#include <hip/hip_runtime.h>
#include <hip/hip_bf16.h>
#include <cstdint>
#include <cstddef>

#define B_ 128
#define S_ 256
#define TOK (B_*S_)   // 32768

typedef _Float16 f16;
typedef _Float16 f16x2 __attribute__((ext_vector_type(2)));
typedef _Float16 half8 __attribute__((ext_vector_type(8)));
typedef __bf16 bf16x8 __attribute__((ext_vector_type(8)));
typedef float  f32x4  __attribute__((ext_vector_type(4)));

__device__ __forceinline__ float sigf(float x) {
    return __builtin_amdgcn_rcpf(1.0f + __expf(-x));
}
__device__ __forceinline__ float tanhfast(float x) {
    return 1.0f - 2.0f * __builtin_amdgcn_rcpf(1.0f + __expf(2.0f * x));
}
__device__ __forceinline__ float bf2f(unsigned short v) {
    union { unsigned u; float f; } c; c.u = ((unsigned)v) << 16; return c.f;
}
__device__ __forceinline__ unsigned short f2bf(float f) {
    return (unsigned short)(__bfloat16_as_ushort(__float2bfloat16(f)));
}
// packed f16 dot2 with f32 accumulate (VOP3P)
__device__ __forceinline__ float dot2(f16x2 a, f16x2 b, float c) {
    float d;
    asm("v_dot2_f32_f16 %0, %1, %2, %3" : "=v"(d) : "v"(a), "v"(b), "v"(c));
    return d;
}
__device__ __forceinline__ f16x2 u2h2(uint32_t v) {
    union { uint32_t u; f16x2 h; } c; c.u = v; return c.h;
}
// LDS-only barrier: skips __syncthreads' implicit vmcnt(0) so in-flight global
// loads (prefetches) and stores survive across the barrier.
__device__ __forceinline__ void barrier_lds() {
    asm volatile("s_waitcnt lgkmcnt(0)\n\ts_barrier" ::: "memory");
}

// ---- K1: char input-gate quads: gin[(dir*100+c)*100 + u*4+g] = b + Wih·emb
__global__ void k_gin(const float* __restrict__ ce,
                      const float* __restrict__ wih_f, const float* __restrict__ b_f,
                      const float* __restrict__ wih_b, const float* __restrict__ b_b,
                      float* __restrict__ gin) {
    int tid = blockIdx.x * blockDim.x + threadIdx.x;
    if (tid >= 200) return;
    int dir = tid / 100, row = tid % 100;   // row = g*25 + u (PyTorch gate order)
    int g = row / 25, u = row - g*25;
    const float* wih = dir ? wih_b : wih_f;
    float bias = dir ? b_b[row] : b_f[row];
    for (int c = 0; c < 100; ++c) {
        float s = bias;
#pragma unroll
        for (int k = 0; k < 25; ++k) s += wih[row*25 + k] * ce[c*25 + k];
        gin[(dir*100 + c)*100 + u*4 + g] = s;
    }
}

// ---- K1b: word-input weights -> bf16 MFMA B-fragments + bias.
__global__ void k_bfrag(const float* __restrict__ wih_f, const float* __restrict__ bf,
                        const float* __restrict__ wih_b, const float* __restrict__ bb,
                        unsigned short* __restrict__ frag, float* __restrict__ bc) {
    int idx = blockIdx.x * blockDim.x + threadIdx.x;
    if (idx < 2*5*25*512) {
        int e  = idx & 7;
        int l  = (idx >> 3) & 63;
        int r  = idx >> 9;          // 0..249
        int nt = r % 25;
        int r2 = r / 25;            // 0..9
        int kc = r2 % 5;
        int d  = r2 / 5;
        int k  = kc*32 + (l >> 4)*8 + e;
        int nl = nt*16 + (l & 15);
        const float* w = d ? wih_b : wih_f;
        float v = (k < 150) ? w[nl*150 + k] : 0.f;
        frag[idx] = f2bf(v);
    }
    if (idx < 800) {
        int d = idx >= 400 ? 1 : 0, r = idx - d*400;
        bc[idx] = d ? bb[r] : bf[r];
    }
}

// ---- K1c: char Whh -> f16 MFMA B-fragments.
__global__ void k_cfrag(const float* __restrict__ whh_f, const float* __restrict__ whh_b,
                        unsigned short* __restrict__ cfrag) {
    int idx = blockIdx.x * blockDim.x + threadIdx.x;
    if (idx >= 2*7*64*8) return;
    int e  = idx & 7;
    int l  = (idx >> 3) & 63;
    int r  = idx >> 9;          // 0..13
    int nt = r % 7;
    int d  = r / 7;
    int k  = (l >> 4)*8 + e;
    int n  = nt*16 + (l & 15);
    const float* w = d ? whh_b : whh_f;
    float v = (n < 100 && k < 25) ? w[n*25 + k] : 0.f;
    union { f16 h; unsigned short s; } c; c.h = (f16)v;
    cfrag[idx] = c.s;
}

// ---- K1e: W1 -> bf16 MFMA B-fragments for k_feats (K padded 200->224).
__global__ void k_ffrag(const float* __restrict__ W1, unsigned short* __restrict__ frag) {
    int idx = blockIdx.x * blockDim.x + threadIdx.x;
    if (idx >= 7*7*512) return;
    int e  = idx & 7;
    int l  = (idx >> 3) & 63;
    int r  = idx >> 9;          // 0..48
    int nt = r % 7;
    int kc = r / 7;
    int k  = kc*32 + (l >> 4)*8 + e;
    int n  = nt*16 + (l & 15);
    float v = (n < 100 && k < 200) ? W1[(size_t)n*200 + k] : 0.f;
    frag[idx] = f2bf(v);
}

// ---- K2: char BiLSTM on MFMA (proven round 9).
__global__ __launch_bounds__(256)
void k_char(
        const unsigned short* __restrict__ cfrag, const float* __restrict__ gin,
        const int* __restrict__ char_ids, const int* __restrict__ word_num,
        float* __restrict__ wfbuf) {
    __shared__ __align__(16) f16  Hh[64][40];    // h state, row stride 40 (16B-aligned)
    __shared__ __align__(16) float Ct[100][68];  // C^T: [gate*25+u][word]
    __shared__ int chlT[16][64];                 // char ids transposed [t][word]
    int wt = blockIdx.x >> 1, dir = blockIdx.x & 1;
    int mb = wt*64;
    int tid = threadIdx.x;
    int wv = tid >> 6, lane = tid & 63, lm = lane & 15, lg = lane >> 4;
    int nt0 = wv, nt1 = wv + 4;
    const f16* cf = (const f16*)cfrag;
    half8 B0 = *(const half8*)&cf[((dir*7 + nt0)*64 + lane)*8];
    half8 B1 = {};
    if (nt1 < 7) B1 = *(const half8*)&cf[((dir*7 + nt1)*64 + lane)*8];
    {
        int w = tid >> 2, j4 = tid & 3;
        int4 v = *(const int4*)&char_ids[(size_t)(mb + w)*16 + j4*4];
        chlT[j4*4+0][w] = v.x; chlT[j4*4+1][w] = v.y;
        chlT[j4*4+2][w] = v.z; chlT[j4*4+3][w] = v.w;
    }
    for (int i = tid; i < 1280; i += 256) ((uint32_t*)Hh)[i] = 0;   // h0=0 + pad
    __syncthreads();
    int ua = tid >> 4;            // 0..15
    int ub = ua + 16;             // valid if <25
    bool hasb = (ub < 25);
    int m0 = (tid & 15)*4;
    float csa[4] = {0,0,0,0}, csb[4] = {0,0,0,0};
    const float* ginD = gin + dir*100*100;
    f32x4 zz = {0.f, 0.f, 0.f, 0.f};
    int t0 = dir ? 15 : 0;
    float4 Ga[4], Gb[4], Na[4], Nb[4];
#pragma unroll
    for (int j = 0; j < 4; ++j) {
        int c = chlT[t0][m0 + j];
        Ga[j] = *(const float4*)&ginD[c*100 + ua*4];
        Gb[j] = hasb ? *(const float4*)&ginD[c*100 + ub*4] : make_float4(0,0,0,0);
    }
#pragma unroll 1
    for (int tt = 0; tt < 16; ++tt) {
        f32x4 a0[4], a1[4];
#pragma unroll
        for (int mf = 0; mf < 4; ++mf) {
            half8 A = *(const half8*)&Hh[mf*16 + lm][lg*8];
            a0[mf] = __builtin_amdgcn_mfma_f32_16x16x32_f16(A, B0, zz, 0, 0, 0);
            a1[mf] = (nt1 < 7)
                ? __builtin_amdgcn_mfma_f32_16x16x32_f16(A, B1, zz, 0, 0, 0) : zz;
        }
#pragma unroll
        for (int mf = 0; mf < 4; ++mf) {
            *(f32x4*)&Ct[nt0*16 + lm][mf*16 + lg*4] = a0[mf];
            if (nt1 < 7 && nt1*16 + lm < 100)
                *(f32x4*)&Ct[nt1*16 + lm][mf*16 + lg*4] = a1[mf];
        }
        if (tt < 15) {
            int tn = dir ? (14 - tt) : (tt + 1);
            int4 cs4 = *(const int4*)&chlT[tn][m0];
            int cj[4] = {cs4.x, cs4.y, cs4.z, cs4.w};
#pragma unroll
            for (int j = 0; j < 4; ++j) {
                Na[j] = *(const float4*)&ginD[cj[j]*100 + ua*4];
                Nb[j] = hasb ? *(const float4*)&ginD[cj[j]*100 + ub*4]
                             : make_float4(0,0,0,0);
            }
        }
        barrier_lds();
        f32x4 Ra[4], Rb[4];
#pragma unroll
        for (int g = 0; g < 4; ++g) {
            Ra[g] = *(const f32x4*)&Ct[g*25 + ua][m0];
            if (hasb) Rb[g] = *(const f32x4*)&Ct[g*25 + ub][m0];
        }
#pragma unroll
        for (int j = 0; j < 4; ++j) {
            float gi = Ra[0][j] + Ga[j].x, gf = Ra[1][j] + Ga[j].y;
            float gg = Ra[2][j] + Ga[j].z, go = Ra[3][j] + Ga[j].w;
            csa[j] = sigf(gf)*csa[j] + sigf(gi)*tanhfast(gg);
            float h = sigf(go)*tanhfast(csa[j]);
            Hh[m0 + j][ua] = (f16)h;
            if (tt == 15) {
                int word = mb + m0 + j, bb = word >> 8, ss = word & 255;
                float mk = (ss < word_num[bb]) ? 1.f : 0.f;
                wfbuf[(size_t)word*152 + 100 + dir*25 + ua] = h*mk;
            }
        }
        if (hasb) {
#pragma unroll
            for (int j = 0; j < 4; ++j) {
                float gi = Rb[0][j] + Gb[j].x, gf = Rb[1][j] + Gb[j].y;
                float gg = Rb[2][j] + Gb[j].z, go = Rb[3][j] + Gb[j].w;
                csb[j] = sigf(gf)*csb[j] + sigf(gi)*tanhfast(gg);
                float h = sigf(go)*tanhfast(csb[j]);
                Hh[m0 + j][ub] = (f16)h;
                if (tt == 15) {
                    int word = mb + m0 + j, bb = word >> 8, ss = word & 255;
                    float mk = (ss < word_num[bb]) ? 1.f : 0.f;
                    wfbuf[(size_t)word*152 + 100 + dir*25 + ub] = h*mk;
                }
            }
        }
        barrier_lds();
        if (tt < 15) {
#pragma unroll
            for (int j = 0; j < 4; ++j) { Ga[j] = Na[j]; Gb[j] = Nb[j]; }
        }
    }
}

// ---- K3: word input gates GEMM on MFMA, embedding gather fused into A-staging.
__global__ __launch_bounds__(256)
void k_gemm_mfma(
        const float* __restrict__ wfbuf, const float* __restrict__ we,
        const int* __restrict__ wids, const unsigned short* __restrict__ frag,
        const float* __restrict__ bc, __hip_bfloat16* __restrict__ gates) {
    __shared__ __align__(16) unsigned short As[64*168];   // 21504 B
    int mt  = blockIdx.x >> 1, dir = blockIdx.x & 1;
    int m0  = mt * 64;
    int tid = threadIdx.x;
    int wv  = tid >> 6;
    int lane = tid & 63;
    int lm  = lane & 15;
    int lg  = lane >> 4;
    {
        int row = tid >> 2, qc = tid & 3;
        const float* embp = we + (size_t)wids[m0 + row]*100;
        const float* chp  = wfbuf + (size_t)(m0 + row)*152;
        unsigned* dst = (unsigned*)As + row*84 + qc*19;
#pragma unroll
        for (int i = 0; i < 19; ++i) {
            int c = qc*38 + 2*i;     // even; emb/char boundary (100) never straddled
            float2 v;
            if (c < 100)       v = *(const float2*)&embp[c];
            else if (c < 150)  v = *(const float2*)&chp[c];
            else               v = make_float2(0.f, 0.f);
            dst[i] = ((unsigned)f2bf(v.y) << 16) | f2bf(v.x);
        }
        if (qc == 3) {   // zero k-pad cols 152..159
            unsigned* z = (unsigned*)As + row*84 + 76;
            z[0] = 0; z[1] = 0; z[2] = 0; z[3] = 0;
        }
    }
    __syncthreads();
    f32x4 acc[7][4] = {};
    const unsigned short* fb = frag + (size_t)dir*(5*25*512);
#pragma unroll
    for (int kc = 0; kc < 5; ++kc) {
        bf16x8 bfr[7];
#pragma unroll
        for (int j = 0; j < 7; ++j) {
            int nt = wv + 4*j;
            bf16x8 v = {};
            if (nt < 25)
                v = *(const bf16x8*)&fb[((size_t)(kc*25 + nt)*64 + lane)*8];
            bfr[j] = v;
        }
        bf16x8 afr[4];
#pragma unroll
        for (int mf = 0; mf < 4; ++mf)
            afr[mf] = *(const bf16x8*)&As[(mf*16 + lm)*168 + kc*32 + lg*8];
#pragma unroll
        for (int j = 0; j < 7; ++j) {
            int nt = wv + 4*j;
            if (nt < 25) {
#pragma unroll
                for (int mf = 0; mf < 4; ++mf)
                    acc[j][mf] = __builtin_amdgcn_mfma_f32_16x16x32_bf16(
                        afr[mf], bfr[j], acc[j][mf], 0, 0, 0);
            }
        }
    }
#pragma unroll
    for (int j = 0; j < 7; ++j) {
        int nt = wv + 4*j;
        if (nt >= 25) continue;
        int n = nt*16 + lm;
        float bias = bc[dir*400 + n];
        int u = n % 100, g = n / 100;
#pragma unroll
        for (int mf = 0; mf < 4; ++mf) {
#pragma unroll
            for (int r = 0; r < 4; ++r) {
                int m = m0 + mf*16 + lg*4 + r;
                gates[((size_t)dir*TOK + m)*400 + u*4 + g]
                    = __float2bfloat16(acc[j][mf][r] + bias);
            }
        }
    }
}

// ---- K4: word BiLSTM, dot2, 2 chains (dir 0/1) per 1024-thread block.
//      v8: round 13's 2-chain merge regressed ONLY because __launch_bounds__(1024)
//      without waves_per_eu let the allocator target 2 blocks/CU (VGPR_Count 44 <
//      52-dword weight array -> per-step weight remat, VALUBusy 35%).
//      amdgpu_waves_per_eu(4,4) pins 4 waves/SIMD = 1 block/CU -> 128-VGPR
//      budget, weights resident again; the co-residency experiment actually runs.
__global__ __launch_bounds__(1024)
__attribute__((amdgpu_waves_per_eu(4, 4)))
void k_word(
        const __hip_bfloat16* __restrict__ gates,
        const float* __restrict__ whh_f, const float* __restrict__ whh_b,
        __hip_bfloat16* __restrict__ wh) {
    int b   = blockIdx.x;
    int tid = threadIdx.x;
    int ch  = tid >> 9;             // chain = dir
    int t5  = tid & 511;            // chain-local thread id
    int wv   = t5 >> 6;             // wave 0..7 within chain
    int lane = t5 & 63;
    int q    = lane >> 4;           // k-quarter: contiguous k in [q*26, q*26+26)
    int u    = wv*16 + (lane & 15); // unit 0..127
    bool act = (u < 100);
    int dir  = ch;
    const float* whh = dir ? whh_b : whh_f;
    __shared__ __align__(16) uint32_t Hs[2][2][64];   // [chain][buf][dword]
    for (int i = tid; i < 256; i += 1024) ((uint32_t*)Hs)[i] = 0;
    f16x2 W[4][13];
#pragma unroll
    for (int gi = 0; gi < 4; ++gi)
#pragma unroll
        for (int i = 0; i < 13; ++i) {
            int k0 = q*26 + 2*i;
            f16x2 v = {};
            if (act) {
                const float* r = &whh[(size_t)(gi*100 + u)*100];
                if (k0 < 100)     v.x = (f16)r[k0];
                if (k0 + 1 < 100) v.y = (f16)r[k0+1];
            }
            W[gi][i] = v;
        }
    int hq = u / 26, hr = u - hq*26;
    int hwofs = hq*32 + hr;     // ushort index into Hs[ch][buf]
    float cst = 0.f;
    const unsigned short* gp = (const unsigned short*)gates
                             + (size_t)(dir*TOK + b*256)*400;   // [t][u*4+gate]
    __syncthreads();
    int t0 = dir ? 255 : 0;
    ushort4 Gc = *(const ushort4*)(gp + (size_t)t0*400 + (act ? u*4 : 0));
    ushort4 Gn = Gc;
#pragma unroll 1
    for (int tt = 0; tt < 256; ++tt) {
        int t = dir ? (255 - tt) : tt;
        if (tt < 255) {
            int tn = dir ? (t - 1) : (t + 1);
            Gn = *(const ushort4*)(gp + (size_t)tn*400 + (act ? u*4 : 0));
        }
        const uint32_t* hb = Hs[ch][tt & 1] + q*16;
        const uint4* hp4 = (const uint4*)hb;
        uint4 hA = hp4[0], hB = hp4[1], hC = hp4[2];
        uint32_t hD = hb[12];
        uint32_t hw[13] = {hA.x, hA.y, hA.z, hA.w,
                           hB.x, hB.y, hB.z, hB.w,
                           hC.x, hC.y, hC.z, hC.w, hD};
        float a0 = 0.f, a1 = 0.f, a2 = 0.f, a3 = 0.f;
#pragma unroll
        for (int i = 0; i < 13; ++i) {
            f16x2 h2 = u2h2(hw[i]);
            a0 = dot2(W[0][i], h2, a0);
            a1 = dot2(W[1][i], h2, a1);
            a2 = dot2(W[2][i], h2, a2);
            a3 = dot2(W[3][i], h2, a3);
        }
        a0 += __shfl_xor(a0, 16, 64); a0 += __shfl_xor(a0, 32, 64);
        a1 += __shfl_xor(a1, 16, 64); a1 += __shfl_xor(a1, 32, 64);
        a2 += __shfl_xor(a2, 16, 64); a2 += __shfl_xor(a2, 32, 64);
        a3 += __shfl_xor(a3, 16, 64); a3 += __shfl_xor(a3, 32, 64);
        float gI = bf2f(Gc.x) + a0, gF = bf2f(Gc.y) + a1;
        float gG = bf2f(Gc.z) + a2, gO = bf2f(Gc.w) + a3;
        cst = sigf(gF)*cst + sigf(gI)*tanhfast(gG);
        float h = sigf(gO)*tanhfast(cst);
        if (act && q == 0) {
            union { f16 hh; unsigned short us; } cv; cv.hh = (f16)h;
            ((unsigned short*)Hs[ch][(tt + 1) & 1])[hwofs] = cv.us;
            wh[(size_t)(b*256 + t)*200 + dir*100 + u] = __float2bfloat16(h);
        }
        barrier_lds();   // LDS-only: prefetch + wh stores stay in flight
        Gc = Gn;
    }
}

// ---- K5: feats on MFMA (proven round 12).
__global__ __launch_bounds__(256) void k_feats(
        const __hip_bfloat16* __restrict__ wh, const unsigned short* __restrict__ frag,
        const float* __restrict__ b1, const float* __restrict__ W2,
        const float* __restrict__ b2, const int* __restrict__ word_num,
        float* __restrict__ feats) {
    __shared__ __align__(16) char smem[29696];   // As [64][232]bf16 = 29696 B
    unsigned short* As = (unsigned short*)smem;  // row stride 232 bf16 (116 dwords)
    float* mids = (float*)smem;                  // later: [64][108] f32 = 27648 B
    int m0  = blockIdx.x * 64;
    int tid = threadIdx.x;
    int wv  = tid >> 6;
    int lane = tid & 63;
    int lm  = lane & 15;
    int lg  = lane >> 4;
    {
        int row = tid >> 2, qc = tid & 3;
        const uint32_t* src = (const uint32_t*)(wh + (size_t)(m0 + row)*200);
        uint32_t* dst = (uint32_t*)As + row*116 + qc*28;
#pragma unroll
        for (int i = 0; i < 28; ++i) {
            int d = qc*28 + i;
            dst[i] = (d < 100) ? src[d] : 0u;
        }
    }
    __syncthreads();
    f32x4 acc[2][4] = {};
#pragma unroll
    for (int kc = 0; kc < 7; ++kc) {
        bf16x8 bfr[2];
#pragma unroll
        for (int j = 0; j < 2; ++j) {
            int nt = wv + 4*j;
            bf16x8 v = {};
            if (nt < 7)
                v = *(const bf16x8*)&frag[((size_t)(kc*7 + nt)*64 + lane)*8];
            bfr[j] = v;
        }
        bf16x8 afr[4];
#pragma unroll
        for (int mf = 0; mf < 4; ++mf)
            afr[mf] = *(const bf16x8*)&As[(mf*16 + lm)*232 + kc*32 + lg*8];
#pragma unroll
        for (int j = 0; j < 2; ++j) {
            int nt = wv + 4*j;
            if (nt < 7) {
#pragma unroll
                for (int mf = 0; mf < 4; ++mf)
                    acc[j][mf] = __builtin_amdgcn_mfma_f32_16x16x32_bf16(
                        afr[mf], bfr[j], acc[j][mf], 0, 0, 0);
            }
        }
    }
    __syncthreads();   // As dead; smem becomes mids
#pragma unroll
    for (int j = 0; j < 2; ++j) {
        int nt = wv + 4*j;
        if (nt >= 7) continue;
        int n = nt*16 + lm;
        if (n >= 100) continue;
        float b1v = b1[n];
#pragma unroll
        for (int mf = 0; mf < 4; ++mf) {
#pragma unroll
            for (int r = 0; r < 4; ++r)
                mids[(mf*16 + lg*4 + r)*108 + n] = tanhfast(acc[j][mf][r] + b1v);
        }
    }
    __syncthreads();
    for (int idx = tid; idx < 576; idx += 256) {
        int tok = idx / 9, lab = idx - tok*9;
        int m = m0 + tok, bb = m >> 8, s = m & 255;
        float v = b2[lab];
        const f32x4* mp = (const f32x4*)&mids[tok*108];
        const float4* wp = (const float4*)(W2 + lab*100);
#pragma unroll
        for (int k = 0; k < 25; ++k) {
            f32x4 mv = mp[k];
            float4 wv4 = wp[k];
            v += mv[0]*wv4.x + mv[1]*wv4.y + mv[2]*wv4.z + mv[3]*wv4.w;
        }
        feats[(size_t)m*12 + lab] = (s < word_num[bb]) ? v : 0.f;
    }
}

// ---- K6: CRF numerator + log-forward recursion. One wave per batch row.
__global__ __launch_bounds__(64) void k_crf(
        const float* __restrict__ feats, const float* __restrict__ T,
        const int* __restrict__ word_num, const int* __restrict__ label_ids,
        float* __restrict__ perb) {
    int b = blockIdx.x, lane = threadIdx.x;
    int n = word_num[b];
    const int*   lab = label_ids + b*256;
    const float* fb  = feats + (size_t)b*256*12;
    float nm = 0.f;
    for (int t = lane; t < n; t += 64) {
        int lt = lab[t];
        int lp = (t == 0) ? 9 : lab[t-1];
        nm += fb[t*12 + lt] + T[lp*11 + lt];
    }
#pragma unroll
    for (int o = 32; o > 0; o >>= 1) nm += __shfl_down(nm, o, 64);
    nm = __shfl(nm, 0, 64);
    nm += T[lab[n-1]*11 + 10];
    int j = lane;
    float Tc[11];
#pragma unroll
    for (int i = 0; i < 11; ++i) Tc[i] = T[i*11 + (j < 11 ? j : 0)];
    float alpha = (j == 9) ? 0.f : -1000.f;
    for (int t = 0; t < n; ++t) {
        float obs = (j < 9) ? fb[t*12 + j] : -1000.f;
        float v[11], mx = -1e30f;
#pragma unroll
        for (int i = 0; i < 11; ++i) { v[i] = __shfl(alpha, i, 64) + Tc[i]; mx = fmaxf(mx, v[i]); }
        float ssum = 0.f;
#pragma unroll
        for (int i = 0; i < 11; ++i) ssum += __expf(v[i] - mx);
        alpha = obs + mx + __logf(ssum);
    }
    float vv[11], mx = -1e30f, ssum = 0.f;
#pragma unroll
    for (int i = 0; i < 11; ++i) { vv[i] = __shfl(alpha, i, 64) + Tc[i]; mx = fmaxf(mx, vv[i]); }
#pragma unroll
    for (int i = 0; i < 11; ++i) ssum += __expf(vv[i] - mx);
    float denom = __shfl(mx + __logf(ssum), 10, 64);
    if (lane == 0) perb[b] = denom - nm;
}

// ---- K7: mean over batch
__global__ void k_reduce(const float* __restrict__ perb, float* __restrict__ out) {
    int t = threadIdx.x;
    float v = perb[t];
#pragma unroll
    for (int o = 32; o > 0; o >>= 1) v += __shfl_down(v, o, 64);
    __shared__ float sm[2];
    if ((t & 63) == 0) sm[t >> 6] = v;
    __syncthreads();
    if (t == 0) out[0] = (sm[0] + sm[1]) * (1.0f/128.0f);
}

extern "C" void kernel_launch(void* const* d_in, const int* in_sizes, int n_in,
                              void* d_out, int out_size, void* d_ws, size_t ws_size,
                              hipStream_t stream) {
    const float* word_emb = (const float*)d_in[0];
    const float* char_emb = (const float*)d_in[1];
    const float* cWih_f   = (const float*)d_in[2];
    const float* cWhh_f   = (const float*)d_in[3];
    const float* cb_f     = (const float*)d_in[4];
    const float* cWih_b   = (const float*)d_in[5];
    const float* cWhh_b   = (const float*)d_in[6];
    const float* cb_b     = (const float*)d_in[7];
    const float* wWih_f   = (const float*)d_in[8];
    const float* wWhh_f   = (const float*)d_in[9];
    const float* wb_f     = (const float*)d_in[10];
    const float* wWih_b   = (const float*)d_in[11];
    const float* wWhh_b   = (const float*)d_in[12];
    const float* wb_b     = (const float*)d_in[13];
    const float* W1       = (const float*)d_in[14];
    const float* b1       = (const float*)d_in[15];
    const float* W2       = (const float*)d_in[16];
    const float* b2       = (const float*)d_in[17];
    const float* T        = (const float*)d_in[18];
    const int* word_num   = (const int*)d_in[19];
    const int* word_ids   = (const int*)d_in[20];
    const int* char_ids   = (const int*)d_in[21];
    const int* label_ids  = (const int*)d_in[22];

    char* ws = (char*)d_ws;
    float* gin            = (float*)(ws);                       //    80,000 B
    float* bc             = (float*)(ws + 566400);              //     3,200 B
    float* wfbuf          = (float*)(ws + 569600);              // 19,922,944 B [32768][152] (cols 100..149 used)
    __hip_bfloat16* gates = (__hip_bfloat16*)(ws + 20492544);   // 52,428,800 B [2][32768][400]
    __hip_bfloat16* wh    = (__hip_bfloat16*)(ws + 72921344);   // 13,107,200 B [32768][200]
    float* feats          = (float*)(ws + 86028544);            //  1,572,864 B [32768][12]
    float* perb           = (float*)(ws + 87601408);            //       512 B
    // cfrag (14,336 B) aliases head of `gates`: k_cfrag -> k_char -> overwritten
    // by k_gemm_mfma (strictly serial).
    unsigned short* cfrag = (unsigned short*)(ws + 20492544);
    // wfrag (256,000 B) aliases head of `wh`: k_bfrag -> k_gemm_mfma -> k_word
    // overwrites wh (serial).
    unsigned short* wfrag = (unsigned short*)(ws + 72921344);
    // ffrag (50,176 B) aliases `gin` (dead after k_char): k_ffrag launched after
    // k_char, consumed by k_feats (serial).
    unsigned short* ffrag = (unsigned short*)(ws);

    k_gin   <<<4, 64, 0, stream>>>(char_emb, cWih_f, cb_f, cWih_b, cb_b, gin);
    k_bfrag <<<(2*5*25*512 + 255)/256, 256, 0, stream>>>(wWih_f, wb_f, wWih_b, wb_b, wfrag, bc);
    k_cfrag <<<(2*7*64*8 + 255)/256, 256, 0, stream>>>(cWhh_f, cWhh_b, cfrag);
    k_char  <<<1024, 256, 0, stream>>>(cfrag, gin, char_ids, word_num, wfbuf);
    k_ffrag <<<(7*7*512 + 255)/256, 256, 0, stream>>>(W1, ffrag);
    k_gemm_mfma<<<1024, 256, 0, stream>>>(wfbuf, word_emb, word_ids, wfrag, bc, gates);
    k_word  <<<128, 1024, 0, stream>>>(gates, wWhh_f, wWhh_b, wh);
    k_feats <<<512, 256, 0, stream>>>(wh, ffrag, b1, W2, b2, word_num, feats);
    k_crf   <<<128, 64, 0, stream>>>(feats, T, word_num, label_ids, perb);
    k_reduce<<<1, 128, 0, stream>>>(perb, (float*)d_out);
}

// Round 16
// 534.971 us; speedup vs baseline: 1.1919x; 1.1919x over previous
//
#include <hip/hip_runtime.h>
#include <hip/hip_bf16.h>
#include <cstdint>
#include <cstddef>

#define B_ 128
#define S_ 256
#define TOK (B_*S_)   // 32768

typedef _Float16 f16;
typedef _Float16 f16x2 __attribute__((ext_vector_type(2)));
typedef _Float16 half8 __attribute__((ext_vector_type(8)));
typedef __bf16 bf16x8 __attribute__((ext_vector_type(8)));
typedef float  f32x4  __attribute__((ext_vector_type(4)));

__device__ __forceinline__ float sigf(float x) {
    return __builtin_amdgcn_rcpf(1.0f + __expf(-x));
}
__device__ __forceinline__ float tanhfast(float x) {
    return 1.0f - 2.0f * __builtin_amdgcn_rcpf(1.0f + __expf(2.0f * x));
}
__device__ __forceinline__ float bf2f(unsigned short v) {
    union { unsigned u; float f; } c; c.u = ((unsigned)v) << 16; return c.f;
}
__device__ __forceinline__ unsigned short f2bf(float f) {
    return (unsigned short)(__bfloat16_as_ushort(__float2bfloat16(f)));
}
// packed f16 dot2 with f32 accumulate (VOP3P)
__device__ __forceinline__ float dot2(f16x2 a, f16x2 b, float c) {
    float d;
    asm("v_dot2_f32_f16 %0, %1, %2, %3" : "=v"(d) : "v"(a), "v"(b), "v"(c));
    return d;
}
__device__ __forceinline__ f16x2 u2h2(uint32_t v) {
    union { uint32_t u; f16x2 h; } c; c.u = v; return c.h;
}
// LDS-only barrier: skips __syncthreads' implicit vmcnt(0) so in-flight global
// loads (prefetches) and stores survive across the barrier.
__device__ __forceinline__ void barrier_lds() {
    asm volatile("s_waitcnt lgkmcnt(0)\n\ts_barrier" ::: "memory");
}

// ---- K1: char input-gate quads: gin[(dir*100+c)*100 + u*4+g] = b + Wih·emb
__global__ void k_gin(const float* __restrict__ ce,
                      const float* __restrict__ wih_f, const float* __restrict__ b_f,
                      const float* __restrict__ wih_b, const float* __restrict__ b_b,
                      float* __restrict__ gin) {
    int tid = blockIdx.x * blockDim.x + threadIdx.x;
    if (tid >= 200) return;
    int dir = tid / 100, row = tid % 100;   // row = g*25 + u (PyTorch gate order)
    int g = row / 25, u = row - g*25;
    const float* wih = dir ? wih_b : wih_f;
    float bias = dir ? b_b[row] : b_f[row];
    for (int c = 0; c < 100; ++c) {
        float s = bias;
#pragma unroll
        for (int k = 0; k < 25; ++k) s += wih[row*25 + k] * ce[c*25 + k];
        gin[(dir*100 + c)*100 + u*4 + g] = s;
    }
}

// ---- K1b: word-input weights -> bf16 MFMA B-fragments + bias.
__global__ void k_bfrag(const float* __restrict__ wih_f, const float* __restrict__ bf,
                        const float* __restrict__ wih_b, const float* __restrict__ bb,
                        unsigned short* __restrict__ frag, float* __restrict__ bc) {
    int idx = blockIdx.x * blockDim.x + threadIdx.x;
    if (idx < 2*5*25*512) {
        int e  = idx & 7;
        int l  = (idx >> 3) & 63;
        int r  = idx >> 9;          // 0..249
        int nt = r % 25;
        int r2 = r / 25;            // 0..9
        int kc = r2 % 5;
        int d  = r2 / 5;
        int k  = kc*32 + (l >> 4)*8 + e;
        int nl = nt*16 + (l & 15);
        const float* w = d ? wih_b : wih_f;
        float v = (k < 150) ? w[nl*150 + k] : 0.f;
        frag[idx] = f2bf(v);
    }
    if (idx < 800) {
        int d = idx >= 400 ? 1 : 0, r = idx - d*400;
        bc[idx] = d ? bb[r] : bf[r];
    }
}

// ---- K1c: char Whh -> f16 MFMA B-fragments.
__global__ void k_cfrag(const float* __restrict__ whh_f, const float* __restrict__ whh_b,
                        unsigned short* __restrict__ cfrag) {
    int idx = blockIdx.x * blockDim.x + threadIdx.x;
    if (idx >= 2*7*64*8) return;
    int e  = idx & 7;
    int l  = (idx >> 3) & 63;
    int r  = idx >> 9;          // 0..13
    int nt = r % 7;
    int d  = r / 7;
    int k  = (l >> 4)*8 + e;
    int n  = nt*16 + (l & 15);
    const float* w = d ? whh_b : whh_f;
    float v = (n < 100 && k < 25) ? w[n*25 + k] : 0.f;
    union { f16 h; unsigned short s; } c; c.h = (f16)v;
    cfrag[idx] = c.s;
}

// ---- K1e: W1 -> bf16 MFMA B-fragments for k_feats (K padded 200->224).
__global__ void k_ffrag(const float* __restrict__ W1, unsigned short* __restrict__ frag) {
    int idx = blockIdx.x * blockDim.x + threadIdx.x;
    if (idx >= 7*7*512) return;
    int e  = idx & 7;
    int l  = (idx >> 3) & 63;
    int r  = idx >> 9;          // 0..48
    int nt = r % 7;
    int kc = r / 7;
    int k  = kc*32 + (l >> 4)*8 + e;
    int n  = nt*16 + (l & 15);
    float v = (n < 100 && k < 200) ? W1[(size_t)n*200 + k] : 0.f;
    frag[idx] = f2bf(v);
}

// ---- K2: char BiLSTM on MFMA (proven round 9).
__global__ __launch_bounds__(256)
void k_char(
        const unsigned short* __restrict__ cfrag, const float* __restrict__ gin,
        const int* __restrict__ char_ids, const int* __restrict__ word_num,
        float* __restrict__ wfbuf) {
    __shared__ __align__(16) f16  Hh[64][40];    // h state, row stride 40 (16B-aligned)
    __shared__ __align__(16) float Ct[100][68];  // C^T: [gate*25+u][word]
    __shared__ int chlT[16][64];                 // char ids transposed [t][word]
    int wt = blockIdx.x >> 1, dir = blockIdx.x & 1;
    int mb = wt*64;
    int tid = threadIdx.x;
    int wv = tid >> 6, lane = tid & 63, lm = lane & 15, lg = lane >> 4;
    int nt0 = wv, nt1 = wv + 4;
    const f16* cf = (const f16*)cfrag;
    half8 B0 = *(const half8*)&cf[((dir*7 + nt0)*64 + lane)*8];
    half8 B1 = {};
    if (nt1 < 7) B1 = *(const half8*)&cf[((dir*7 + nt1)*64 + lane)*8];
    {
        int w = tid >> 2, j4 = tid & 3;
        int4 v = *(const int4*)&char_ids[(size_t)(mb + w)*16 + j4*4];
        chlT[j4*4+0][w] = v.x; chlT[j4*4+1][w] = v.y;
        chlT[j4*4+2][w] = v.z; chlT[j4*4+3][w] = v.w;
    }
    for (int i = tid; i < 1280; i += 256) ((uint32_t*)Hh)[i] = 0;   // h0=0 + pad
    __syncthreads();
    int ua = tid >> 4;            // 0..15
    int ub = ua + 16;             // valid if <25
    bool hasb = (ub < 25);
    int m0 = (tid & 15)*4;
    float csa[4] = {0,0,0,0}, csb[4] = {0,0,0,0};
    const float* ginD = gin + dir*100*100;
    f32x4 zz = {0.f, 0.f, 0.f, 0.f};
    int t0 = dir ? 15 : 0;
    float4 Ga[4], Gb[4], Na[4], Nb[4];
#pragma unroll
    for (int j = 0; j < 4; ++j) {
        int c = chlT[t0][m0 + j];
        Ga[j] = *(const float4*)&ginD[c*100 + ua*4];
        Gb[j] = hasb ? *(const float4*)&ginD[c*100 + ub*4] : make_float4(0,0,0,0);
    }
#pragma unroll 1
    for (int tt = 0; tt < 16; ++tt) {
        f32x4 a0[4], a1[4];
#pragma unroll
        for (int mf = 0; mf < 4; ++mf) {
            half8 A = *(const half8*)&Hh[mf*16 + lm][lg*8];
            a0[mf] = __builtin_amdgcn_mfma_f32_16x16x32_f16(A, B0, zz, 0, 0, 0);
            a1[mf] = (nt1 < 7)
                ? __builtin_amdgcn_mfma_f32_16x16x32_f16(A, B1, zz, 0, 0, 0) : zz;
        }
#pragma unroll
        for (int mf = 0; mf < 4; ++mf) {
            *(f32x4*)&Ct[nt0*16 + lm][mf*16 + lg*4] = a0[mf];
            if (nt1 < 7 && nt1*16 + lm < 100)
                *(f32x4*)&Ct[nt1*16 + lm][mf*16 + lg*4] = a1[mf];
        }
        if (tt < 15) {
            int tn = dir ? (14 - tt) : (tt + 1);
            int4 cs4 = *(const int4*)&chlT[tn][m0];
            int cj[4] = {cs4.x, cs4.y, cs4.z, cs4.w};
#pragma unroll
            for (int j = 0; j < 4; ++j) {
                Na[j] = *(const float4*)&ginD[cj[j]*100 + ua*4];
                Nb[j] = hasb ? *(const float4*)&ginD[cj[j]*100 + ub*4]
                             : make_float4(0,0,0,0);
            }
        }
        barrier_lds();
        f32x4 Ra[4], Rb[4];
#pragma unroll
        for (int g = 0; g < 4; ++g) {
            Ra[g] = *(const f32x4*)&Ct[g*25 + ua][m0];
            if (hasb) Rb[g] = *(const f32x4*)&Ct[g*25 + ub][m0];
        }
#pragma unroll
        for (int j = 0; j < 4; ++j) {
            float gi = Ra[0][j] + Ga[j].x, gf = Ra[1][j] + Ga[j].y;
            float gg = Ra[2][j] + Ga[j].z, go = Ra[3][j] + Ga[j].w;
            csa[j] = sigf(gf)*csa[j] + sigf(gi)*tanhfast(gg);
            float h = sigf(go)*tanhfast(csa[j]);
            Hh[m0 + j][ua] = (f16)h;
            if (tt == 15) {
                int word = mb + m0 + j, bb = word >> 8, ss = word & 255;
                float mk = (ss < word_num[bb]) ? 1.f : 0.f;
                wfbuf[(size_t)word*152 + 100 + dir*25 + ua] = h*mk;
            }
        }
        if (hasb) {
#pragma unroll
            for (int j = 0; j < 4; ++j) {
                float gi = Rb[0][j] + Gb[j].x, gf = Rb[1][j] + Gb[j].y;
                float gg = Rb[2][j] + Gb[j].z, go = Rb[3][j] + Gb[j].w;
                csb[j] = sigf(gf)*csb[j] + sigf(gi)*tanhfast(gg);
                float h = sigf(go)*tanhfast(csb[j]);
                Hh[m0 + j][ub] = (f16)h;
                if (tt == 15) {
                    int word = mb + m0 + j, bb = word >> 8, ss = word & 255;
                    float mk = (ss < word_num[bb]) ? 1.f : 0.f;
                    wfbuf[(size_t)word*152 + 100 + dir*25 + ub] = h*mk;
                }
            }
        }
        barrier_lds();
        if (tt < 15) {
#pragma unroll
            for (int j = 0; j < 4; ++j) { Ga[j] = Na[j]; Gb[j] = Nb[j]; }
        }
    }
}

// ---- K3: word input gates GEMM on MFMA, embedding gather fused into A-staging.
__global__ __launch_bounds__(256)
void k_gemm_mfma(
        const float* __restrict__ wfbuf, const float* __restrict__ we,
        const int* __restrict__ wids, const unsigned short* __restrict__ frag,
        const float* __restrict__ bc, __hip_bfloat16* __restrict__ gates) {
    __shared__ __align__(16) unsigned short As[64*168];   // 21504 B
    int mt  = blockIdx.x >> 1, dir = blockIdx.x & 1;
    int m0  = mt * 64;
    int tid = threadIdx.x;
    int wv  = tid >> 6;
    int lane = tid & 63;
    int lm  = lane & 15;
    int lg  = lane >> 4;
    {
        int row = tid >> 2, qc = tid & 3;
        const float* embp = we + (size_t)wids[m0 + row]*100;
        const float* chp  = wfbuf + (size_t)(m0 + row)*152;
        unsigned* dst = (unsigned*)As + row*84 + qc*19;
#pragma unroll
        for (int i = 0; i < 19; ++i) {
            int c = qc*38 + 2*i;     // even; emb/char boundary (100) never straddled
            float2 v;
            if (c < 100)       v = *(const float2*)&embp[c];
            else if (c < 150)  v = *(const float2*)&chp[c];
            else               v = make_float2(0.f, 0.f);
            dst[i] = ((unsigned)f2bf(v.y) << 16) | f2bf(v.x);
        }
        if (qc == 3) {   // zero k-pad cols 152..159
            unsigned* z = (unsigned*)As + row*84 + 76;
            z[0] = 0; z[1] = 0; z[2] = 0; z[3] = 0;
        }
    }
    __syncthreads();
    f32x4 acc[7][4] = {};
    const unsigned short* fb = frag + (size_t)dir*(5*25*512);
#pragma unroll
    for (int kc = 0; kc < 5; ++kc) {
        bf16x8 bfr[7];
#pragma unroll
        for (int j = 0; j < 7; ++j) {
            int nt = wv + 4*j;
            bf16x8 v = {};
            if (nt < 25)
                v = *(const bf16x8*)&fb[((size_t)(kc*25 + nt)*64 + lane)*8];
            bfr[j] = v;
        }
        bf16x8 afr[4];
#pragma unroll
        for (int mf = 0; mf < 4; ++mf)
            afr[mf] = *(const bf16x8*)&As[(mf*16 + lm)*168 + kc*32 + lg*8];
#pragma unroll
        for (int j = 0; j < 7; ++j) {
            int nt = wv + 4*j;
            if (nt < 25) {
#pragma unroll
                for (int mf = 0; mf < 4; ++mf)
                    acc[j][mf] = __builtin_amdgcn_mfma_f32_16x16x32_bf16(
                        afr[mf], bfr[j], acc[j][mf], 0, 0, 0);
            }
        }
    }
#pragma unroll
    for (int j = 0; j < 7; ++j) {
        int nt = wv + 4*j;
        if (nt >= 25) continue;
        int n = nt*16 + lm;
        float bias = bc[dir*400 + n];
        int u = n % 100, g = n / 100;
#pragma unroll
        for (int mf = 0; mf < 4; ++mf) {
#pragma unroll
            for (int r = 0; r < 4; ++r) {
                int m = m0 + mf*16 + lg*4 + r;
                gates[((size_t)dir*TOK + m)*400 + u*4 + g]
                    = __float2bfloat16(acc[j][mf][r] + bias);
            }
        }
    }
}

// ---- K4: word BiLSTM — dot2, 512 threads, waves_per_eu(2,2), 88 VGPR.
//      PERMANENTLY FROZEN at ~200 µs. Established: (a) this is the VALU
//      quarter-rate dot2 issue floor + exposed per-step overhead; (b) recurrent
//      MFMA is latency-dead (442 µs, r10); (c) 2-chain/1024-thr co-residency
//      fails twice via allocator weight-remat (VGPR 44/52 < footprint, r13/r14).
__global__ __launch_bounds__(512)
__attribute__((amdgpu_waves_per_eu(2, 2)))
void k_word(
        const __hip_bfloat16* __restrict__ gates,
        const float* __restrict__ whh_f, const float* __restrict__ whh_b,
        __hip_bfloat16* __restrict__ wh) {
    int b = blockIdx.x >> 1, dir = blockIdx.x & 1;
    int tid = threadIdx.x;
    int wv   = tid >> 6;            // wave 0..7
    int lane = tid & 63;
    int q    = lane >> 4;           // k-quarter: contiguous k in [q*26, q*26+26)
    int u    = wv*16 + (lane & 15); // unit 0..127
    bool act = (u < 100);
    const float* whh = dir ? whh_b : whh_f;
    __shared__ __align__(16) uint32_t Hs[2][64];
    for (int i = tid; i < 128; i += 512) ((uint32_t*)Hs)[i] = 0;
    f16x2 W[4][13];
#pragma unroll
    for (int gi = 0; gi < 4; ++gi)
#pragma unroll
        for (int i = 0; i < 13; ++i) {
            int k0 = q*26 + 2*i;
            f16x2 v = {};
            if (act) {
                const float* r = &whh[(size_t)(gi*100 + u)*100];
                if (k0 < 100)     v.x = (f16)r[k0];
                if (k0 + 1 < 100) v.y = (f16)r[k0+1];
            }
            W[gi][i] = v;
        }
    int hq = u / 26, hr = u - hq*26;
    int hwofs = hq*32 + hr;     // ushort index into Hs[buf]
    float cst = 0.f;
    const unsigned short* gp = (const unsigned short*)gates
                             + (size_t)(dir*TOK + b*256)*400;   // [t][u*4+gate]
    __syncthreads();
    int t0 = dir ? 255 : 0;
    ushort4 Gc = *(const ushort4*)(gp + (size_t)t0*400 + (act ? u*4 : 0));
    ushort4 Gn = Gc;
#pragma unroll 1
    for (int tt = 0; tt < 256; ++tt) {
        int t = dir ? (255 - tt) : tt;
        if (tt < 255) {
            int tn = dir ? (t - 1) : (t + 1);
            Gn = *(const ushort4*)(gp + (size_t)tn*400 + (act ? u*4 : 0));
        }
        const uint32_t* hb = Hs[tt & 1] + q*16;
        const uint4* hp4 = (const uint4*)hb;
        uint4 hA = hp4[0], hB = hp4[1], hC = hp4[2];
        uint32_t hD = hb[12];
        uint32_t hw[13] = {hA.x, hA.y, hA.z, hA.w,
                           hB.x, hB.y, hB.z, hB.w,
                           hC.x, hC.y, hC.z, hC.w, hD};
        float a0 = 0.f, a1 = 0.f, a2 = 0.f, a3 = 0.f;
#pragma unroll
        for (int i = 0; i < 13; ++i) {
            f16x2 h2 = u2h2(hw[i]);
            a0 = dot2(W[0][i], h2, a0);
            a1 = dot2(W[1][i], h2, a1);
            a2 = dot2(W[2][i], h2, a2);
            a3 = dot2(W[3][i], h2, a3);
        }
        a0 += __shfl_xor(a0, 16, 64); a0 += __shfl_xor(a0, 32, 64);
        a1 += __shfl_xor(a1, 16, 64); a1 += __shfl_xor(a1, 32, 64);
        a2 += __shfl_xor(a2, 16, 64); a2 += __shfl_xor(a2, 32, 64);
        a3 += __shfl_xor(a3, 16, 64); a3 += __shfl_xor(a3, 32, 64);
        float gI = bf2f(Gc.x) + a0, gF = bf2f(Gc.y) + a1;
        float gG = bf2f(Gc.z) + a2, gO = bf2f(Gc.w) + a3;
        cst = sigf(gF)*cst + sigf(gI)*tanhfast(gG);
        float h = sigf(gO)*tanhfast(cst);
        if (act && q == 0) {
            union { f16 hh; unsigned short us; } cv; cv.hh = (f16)h;
            ((unsigned short*)Hs[(tt + 1) & 1])[hwofs] = cv.us;
            wh[(size_t)(b*256 + t)*200 + dir*100 + u] = __float2bfloat16(h);
        }
        barrier_lds();   // LDS-only: prefetch + wh stores stay in flight
        Gc = Gn;
    }
}

// ---- K5: feats on MFMA (proven round 12).
__global__ __launch_bounds__(256) void k_feats(
        const __hip_bfloat16* __restrict__ wh, const unsigned short* __restrict__ frag,
        const float* __restrict__ b1, const float* __restrict__ W2,
        const float* __restrict__ b2, const int* __restrict__ word_num,
        float* __restrict__ feats) {
    __shared__ __align__(16) char smem[29696];   // As [64][232]bf16 = 29696 B
    unsigned short* As = (unsigned short*)smem;  // row stride 232 bf16 (116 dwords)
    float* mids = (float*)smem;                  // later: [64][108] f32 = 27648 B
    int m0  = blockIdx.x * 64;
    int tid = threadIdx.x;
    int wv  = tid >> 6;
    int lane = tid & 63;
    int lm  = lane & 15;
    int lg  = lane >> 4;
    {
        int row = tid >> 2, qc = tid & 3;
        const uint32_t* src = (const uint32_t*)(wh + (size_t)(m0 + row)*200);
        uint32_t* dst = (uint32_t*)As + row*116 + qc*28;
#pragma unroll
        for (int i = 0; i < 28; ++i) {
            int d = qc*28 + i;
            dst[i] = (d < 100) ? src[d] : 0u;
        }
    }
    __syncthreads();
    f32x4 acc[2][4] = {};
#pragma unroll
    for (int kc = 0; kc < 7; ++kc) {
        bf16x8 bfr[2];
#pragma unroll
        for (int j = 0; j < 2; ++j) {
            int nt = wv + 4*j;
            bf16x8 v = {};
            if (nt < 7)
                v = *(const bf16x8*)&frag[((size_t)(kc*7 + nt)*64 + lane)*8];
            bfr[j] = v;
        }
        bf16x8 afr[4];
#pragma unroll
        for (int mf = 0; mf < 4; ++mf)
            afr[mf] = *(const bf16x8*)&As[(mf*16 + lm)*232 + kc*32 + lg*8];
#pragma unroll
        for (int j = 0; j < 2; ++j) {
            int nt = wv + 4*j;
            if (nt < 7) {
#pragma unroll
                for (int mf = 0; mf < 4; ++mf)
                    acc[j][mf] = __builtin_amdgcn_mfma_f32_16x16x32_bf16(
                        afr[mf], bfr[j], acc[j][mf], 0, 0, 0);
            }
        }
    }
    __syncthreads();   // As dead; smem becomes mids
#pragma unroll
    for (int j = 0; j < 2; ++j) {
        int nt = wv + 4*j;
        if (nt >= 7) continue;
        int n = nt*16 + lm;
        if (n >= 100) continue;
        float b1v = b1[n];
#pragma unroll
        for (int mf = 0; mf < 4; ++mf) {
#pragma unroll
            for (int r = 0; r < 4; ++r)
                mids[(mf*16 + lg*4 + r)*108 + n] = tanhfast(acc[j][mf][r] + b1v);
        }
    }
    __syncthreads();
    for (int idx = tid; idx < 576; idx += 256) {
        int tok = idx / 9, lab = idx - tok*9;
        int m = m0 + tok, bb = m >> 8, s = m & 255;
        float v = b2[lab];
        const f32x4* mp = (const f32x4*)&mids[tok*108];
        const float4* wp = (const float4*)(W2 + lab*100);
#pragma unroll
        for (int k = 0; k < 25; ++k) {
            f32x4 mv = mp[k];
            float4 wv4 = wp[k];
            v += mv[0]*wv4.x + mv[1]*wv4.y + mv[2]*wv4.z + mv[3]*wv4.w;
        }
        feats[(size_t)m*12 + lab] = (s < word_num[bb]) ? v : 0.f;
    }
}

// ---- K6: CRF numerator + log-forward recursion. One wave per batch row.
__global__ __launch_bounds__(64) void k_crf(
        const float* __restrict__ feats, const float* __restrict__ T,
        const int* __restrict__ word_num, const int* __restrict__ label_ids,
        float* __restrict__ perb) {
    int b = blockIdx.x, lane = threadIdx.x;
    int n = word_num[b];
    const int*   lab = label_ids + b*256;
    const float* fb  = feats + (size_t)b*256*12;
    float nm = 0.f;
    for (int t = lane; t < n; t += 64) {
        int lt = lab[t];
        int lp = (t == 0) ? 9 : lab[t-1];
        nm += fb[t*12 + lt] + T[lp*11 + lt];
    }
#pragma unroll
    for (int o = 32; o > 0; o >>= 1) nm += __shfl_down(nm, o, 64);
    nm = __shfl(nm, 0, 64);
    nm += T[lab[n-1]*11 + 10];
    int j = lane;
    float Tc[11];
#pragma unroll
    for (int i = 0; i < 11; ++i) Tc[i] = T[i*11 + (j < 11 ? j : 0)];
    float alpha = (j == 9) ? 0.f : -1000.f;
    for (int t = 0; t < n; ++t) {
        float obs = (j < 9) ? fb[t*12 + j] : -1000.f;
        float v[11], mx = -1e30f;
#pragma unroll
        for (int i = 0; i < 11; ++i) { v[i] = __shfl(alpha, i, 64) + Tc[i]; mx = fmaxf(mx, v[i]); }
        float ssum = 0.f;
#pragma unroll
        for (int i = 0; i < 11; ++i) ssum += __expf(v[i] - mx);
        alpha = obs + mx + __logf(ssum);
    }
    float vv[11], mx = -1e30f, ssum = 0.f;
#pragma unroll
    for (int i = 0; i < 11; ++i) { vv[i] = __shfl(alpha, i, 64) + Tc[i]; mx = fmaxf(mx, vv[i]); }
#pragma unroll
    for (int i = 0; i < 11; ++i) ssum += __expf(vv[i] - mx);
    float denom = __shfl(mx + __logf(ssum), 10, 64);
    if (lane == 0) perb[b] = denom - nm;
}

// ---- K7: mean over batch
__global__ void k_reduce(const float* __restrict__ perb, float* __restrict__ out) {
    int t = threadIdx.x;
    float v = perb[t];
#pragma unroll
    for (int o = 32; o > 0; o >>= 1) v += __shfl_down(v, o, 64);
    __shared__ float sm[2];
    if ((t & 63) == 0) sm[t >> 6] = v;
    __syncthreads();
    if (t == 0) out[0] = (sm[0] + sm[1]) * (1.0f/128.0f);
}

extern "C" void kernel_launch(void* const* d_in, const int* in_sizes, int n_in,
                              void* d_out, int out_size, void* d_ws, size_t ws_size,
                              hipStream_t stream) {
    const float* word_emb = (const float*)d_in[0];
    const float* char_emb = (const float*)d_in[1];
    const float* cWih_f   = (const float*)d_in[2];
    const float* cWhh_f   = (const float*)d_in[3];
    const float* cb_f     = (const float*)d_in[4];
    const float* cWih_b   = (const float*)d_in[5];
    const float* cWhh_b   = (const float*)d_in[6];
    const float* cb_b     = (const float*)d_in[7];
    const float* wWih_f   = (const float*)d_in[8];
    const float* wWhh_f   = (const float*)d_in[9];
    const float* wb_f     = (const float*)d_in[10];
    const float* wWih_b   = (const float*)d_in[11];
    const float* wWhh_b   = (const float*)d_in[12];
    const float* wb_b     = (const float*)d_in[13];
    const float* W1       = (const float*)d_in[14];
    const float* b1       = (const float*)d_in[15];
    const float* W2       = (const float*)d_in[16];
    const float* b2       = (const float*)d_in[17];
    const float* T        = (const float*)d_in[18];
    const int* word_num   = (const int*)d_in[19];
    const int* word_ids   = (const int*)d_in[20];
    const int* char_ids   = (const int*)d_in[21];
    const int* label_ids  = (const int*)d_in[22];

    char* ws = (char*)d_ws;
    float* gin            = (float*)(ws);                       //    80,000 B
    float* bc             = (float*)(ws + 566400);              //     3,200 B
    float* wfbuf          = (float*)(ws + 569600);              // 19,922,944 B [32768][152] (cols 100..149 used)
    __hip_bfloat16* gates = (__hip_bfloat16*)(ws + 20492544);   // 52,428,800 B [2][32768][400]
    __hip_bfloat16* wh    = (__hip_bfloat16*)(ws + 72921344);   // 13,107,200 B [32768][200]
    float* feats          = (float*)(ws + 86028544);            //  1,572,864 B [32768][12]
    float* perb           = (float*)(ws + 87601408);            //       512 B
    // cfrag (14,336 B) aliases head of `gates`: k_cfrag -> k_char -> overwritten
    // by k_gemm_mfma (strictly serial).
    unsigned short* cfrag = (unsigned short*)(ws + 20492544);
    // wfrag (256,000 B) aliases head of `wh`: k_bfrag -> k_gemm_mfma -> k_word
    // overwrites wh (serial).
    unsigned short* wfrag = (unsigned short*)(ws + 72921344);
    // ffrag (50,176 B) aliases `gin` (dead after k_char): k_ffrag launched after
    // k_char, consumed by k_feats (serial).
    unsigned short* ffrag = (unsigned short*)(ws);

    k_gin   <<<4, 64, 0, stream>>>(char_emb, cWih_f, cb_f, cWih_b, cb_b, gin);
    k_bfrag <<<(2*5*25*512 + 255)/256, 256, 0, stream>>>(wWih_f, wb_f, wWih_b, wb_b, wfrag, bc);
    k_cfrag <<<(2*7*64*8 + 255)/256, 256, 0, stream>>>(cWhh_f, cWhh_b, cfrag);
    k_char  <<<1024, 256, 0, stream>>>(cfrag, gin, char_ids, word_num, wfbuf);
    k_ffrag <<<(7*7*512 + 255)/256, 256, 0, stream>>>(W1, ffrag);
    k_gemm_mfma<<<1024, 256, 0, stream>>>(wfbuf, word_emb, word_ids, wfrag, bc, gates);
    k_word  <<<256, 512, 0, stream>>>(gates, wWhh_f, wWhh_b, wh);
    k_feats <<<512, 256, 0, stream>>>(wh, ffrag, b1, W2, b2, word_num, feats);
    k_crf   <<<128, 64, 0, stream>>>(feats, T, word_num, label_ids, perb);
    k_reduce<<<1, 128, 0, stream>>>(perb, (float*)d_out);
}

// Round 17
// 522.973 us; speedup vs baseline: 1.2192x; 1.0229x over previous
//
#include <hip/hip_runtime.h>
#include <hip/hip_bf16.h>
#include <cstdint>
#include <cstddef>

#define B_ 128
#define S_ 256
#define TOK (B_*S_)   // 32768

typedef _Float16 f16;
typedef _Float16 f16x2 __attribute__((ext_vector_type(2)));
typedef _Float16 half8 __attribute__((ext_vector_type(8)));
typedef __bf16 bf16x8 __attribute__((ext_vector_type(8)));
typedef float  f32x4  __attribute__((ext_vector_type(4)));

__device__ __forceinline__ float sigf(float x) {
    return __builtin_amdgcn_rcpf(1.0f + __expf(-x));
}
__device__ __forceinline__ float tanhfast(float x) {
    return 1.0f - 2.0f * __builtin_amdgcn_rcpf(1.0f + __expf(2.0f * x));
}
__device__ __forceinline__ float bf2f(unsigned short v) {
    union { unsigned u; float f; } c; c.u = ((unsigned)v) << 16; return c.f;
}
__device__ __forceinline__ unsigned short f2bf(float f) {
    return (unsigned short)(__bfloat16_as_ushort(__float2bfloat16(f)));
}
// packed f16 dot2 with f32 accumulate (VOP3P)
__device__ __forceinline__ float dot2(f16x2 a, f16x2 b, float c) {
    float d;
    asm("v_dot2_f32_f16 %0, %1, %2, %3" : "=v"(d) : "v"(a), "v"(b), "v"(c));
    return d;
}
__device__ __forceinline__ f16x2 u2h2(uint32_t v) {
    union { uint32_t u; f16x2 h; } c; c.u = v; return c.h;
}
// LDS-only barrier: skips __syncthreads' implicit vmcnt(0) so in-flight global
// loads (prefetches) and stores survive across the barrier.
__device__ __forceinline__ void barrier_lds() {
    asm volatile("s_waitcnt lgkmcnt(0)\n\ts_barrier" ::: "memory");
}

// ---- K1: fused prep — one launch, blocks dispatch by range:
//      blk 0        : gin quads (200 workers, heavy)
//      blk 1..250   : word-Wih bf16 fragments + bias (64000 elems)
//      blk 251..278 : char-Whh f16 fragments (7168)
//      blk 279..376 : W1 bf16 fragments (25088)
//      Replaces 4 serialized micro-launches; ffrag output moved to its own
//      region so ordering vs gin no longer matters.
__global__ __launch_bounds__(256) void k_prep(
        const float* __restrict__ ce,
        const float* __restrict__ cWih_f, const float* __restrict__ cb_f,
        const float* __restrict__ cWih_b, const float* __restrict__ cb_b,
        const float* __restrict__ wWih_f, const float* __restrict__ wb_f,
        const float* __restrict__ wWih_b, const float* __restrict__ wb_b,
        const float* __restrict__ cWhh_f, const float* __restrict__ cWhh_b,
        const float* __restrict__ W1,
        float* __restrict__ gin, unsigned short* __restrict__ wfrag,
        float* __restrict__ bc, unsigned short* __restrict__ cfrag,
        unsigned short* __restrict__ ffrag) {
    int blk = blockIdx.x, tid = threadIdx.x;
    if (blk == 0) {
        // gin[(dir*100+c)*100 + u*4+g] = b + Wih·emb (row = g*25+u, PyTorch order)
        if (tid < 200) {
            int dir = tid / 100, row = tid % 100;
            int g = row / 25, u = row - g*25;
            const float* wih = dir ? cWih_b : cWih_f;
            float bias = dir ? cb_b[row] : cb_f[row];
            for (int c = 0; c < 100; ++c) {
                float s = bias;
#pragma unroll
                for (int k = 0; k < 25; ++k) s += wih[row*25 + k] * ce[c*25 + k];
                gin[(dir*100 + c)*100 + u*4 + g] = s;
            }
        }
    } else if (blk < 251) {
        int idx = (blk - 1)*256 + tid;          // 0..63999
        if (idx < 2*5*25*512) {
            int e  = idx & 7;
            int l  = (idx >> 3) & 63;
            int r  = idx >> 9;
            int nt = r % 25;
            int r2 = r / 25;
            int kc = r2 % 5;
            int d  = r2 / 5;
            int k  = kc*32 + (l >> 4)*8 + e;
            int nl = nt*16 + (l & 15);
            const float* w = d ? wWih_b : wWih_f;
            float v = (k < 150) ? w[nl*150 + k] : 0.f;
            wfrag[idx] = f2bf(v);
        }
        if (idx < 800) {
            int d = idx >= 400 ? 1 : 0, r = idx - d*400;
            bc[idx] = d ? wb_b[r] : wb_f[r];
        }
    } else if (blk < 279) {
        int idx = (blk - 251)*256 + tid;        // 0..7167
        if (idx < 2*7*64*8) {
            int e  = idx & 7;
            int l  = (idx >> 3) & 63;
            int r  = idx >> 9;
            int nt = r % 7;
            int d  = r / 7;
            int k  = (l >> 4)*8 + e;
            int n  = nt*16 + (l & 15);
            const float* w = d ? cWhh_b : cWhh_f;
            float v = (n < 100 && k < 25) ? w[n*25 + k] : 0.f;
            union { f16 h; unsigned short s; } c; c.h = (f16)v;
            cfrag[idx] = c.s;
        }
    } else {
        int idx = (blk - 279)*256 + tid;        // 0..25087
        if (idx < 7*7*512) {
            int e  = idx & 7;
            int l  = (idx >> 3) & 63;
            int r  = idx >> 9;
            int nt = r % 7;
            int kc = r / 7;
            int k  = kc*32 + (l >> 4)*8 + e;
            int n  = nt*16 + (l & 15);
            float v = (n < 100 && k < 200) ? W1[(size_t)n*200 + k] : 0.f;
            ffrag[idx] = f2bf(v);
        }
    }
}

// ---- K2: char BiLSTM on MFMA (proven round 9).
__global__ __launch_bounds__(256)
void k_char(
        const unsigned short* __restrict__ cfrag, const float* __restrict__ gin,
        const int* __restrict__ char_ids, const int* __restrict__ word_num,
        float* __restrict__ wfbuf) {
    __shared__ __align__(16) f16  Hh[64][40];    // h state, row stride 40 (16B-aligned)
    __shared__ __align__(16) float Ct[100][68];  // C^T: [gate*25+u][word]
    __shared__ int chlT[16][64];                 // char ids transposed [t][word]
    int wt = blockIdx.x >> 1, dir = blockIdx.x & 1;
    int mb = wt*64;
    int tid = threadIdx.x;
    int wv = tid >> 6, lane = tid & 63, lm = lane & 15, lg = lane >> 4;
    int nt0 = wv, nt1 = wv + 4;
    const f16* cf = (const f16*)cfrag;
    half8 B0 = *(const half8*)&cf[((dir*7 + nt0)*64 + lane)*8];
    half8 B1 = {};
    if (nt1 < 7) B1 = *(const half8*)&cf[((dir*7 + nt1)*64 + lane)*8];
    {
        int w = tid >> 2, j4 = tid & 3;
        int4 v = *(const int4*)&char_ids[(size_t)(mb + w)*16 + j4*4];
        chlT[j4*4+0][w] = v.x; chlT[j4*4+1][w] = v.y;
        chlT[j4*4+2][w] = v.z; chlT[j4*4+3][w] = v.w;
    }
    for (int i = tid; i < 1280; i += 256) ((uint32_t*)Hh)[i] = 0;   // h0=0 + pad
    __syncthreads();
    int ua = tid >> 4;            // 0..15
    int ub = ua + 16;             // valid if <25
    bool hasb = (ub < 25);
    int m0 = (tid & 15)*4;
    float csa[4] = {0,0,0,0}, csb[4] = {0,0,0,0};
    const float* ginD = gin + dir*100*100;
    f32x4 zz = {0.f, 0.f, 0.f, 0.f};
    int t0 = dir ? 15 : 0;
    float4 Ga[4], Gb[4], Na[4], Nb[4];
#pragma unroll
    for (int j = 0; j < 4; ++j) {
        int c = chlT[t0][m0 + j];
        Ga[j] = *(const float4*)&ginD[c*100 + ua*4];
        Gb[j] = hasb ? *(const float4*)&ginD[c*100 + ub*4] : make_float4(0,0,0,0);
    }
#pragma unroll 1
    for (int tt = 0; tt < 16; ++tt) {
        f32x4 a0[4], a1[4];
#pragma unroll
        for (int mf = 0; mf < 4; ++mf) {
            half8 A = *(const half8*)&Hh[mf*16 + lm][lg*8];
            a0[mf] = __builtin_amdgcn_mfma_f32_16x16x32_f16(A, B0, zz, 0, 0, 0);
            a1[mf] = (nt1 < 7)
                ? __builtin_amdgcn_mfma_f32_16x16x32_f16(A, B1, zz, 0, 0, 0) : zz;
        }
#pragma unroll
        for (int mf = 0; mf < 4; ++mf) {
            *(f32x4*)&Ct[nt0*16 + lm][mf*16 + lg*4] = a0[mf];
            if (nt1 < 7 && nt1*16 + lm < 100)
                *(f32x4*)&Ct[nt1*16 + lm][mf*16 + lg*4] = a1[mf];
        }
        if (tt < 15) {
            int tn = dir ? (14 - tt) : (tt + 1);
            int4 cs4 = *(const int4*)&chlT[tn][m0];
            int cj[4] = {cs4.x, cs4.y, cs4.z, cs4.w};
#pragma unroll
            for (int j = 0; j < 4; ++j) {
                Na[j] = *(const float4*)&ginD[cj[j]*100 + ua*4];
                Nb[j] = hasb ? *(const float4*)&ginD[cj[j]*100 + ub*4]
                             : make_float4(0,0,0,0);
            }
        }
        barrier_lds();
        f32x4 Ra[4], Rb[4];
#pragma unroll
        for (int g = 0; g < 4; ++g) {
            Ra[g] = *(const f32x4*)&Ct[g*25 + ua][m0];
            if (hasb) Rb[g] = *(const f32x4*)&Ct[g*25 + ub][m0];
        }
#pragma unroll
        for (int j = 0; j < 4; ++j) {
            float gi = Ra[0][j] + Ga[j].x, gf = Ra[1][j] + Ga[j].y;
            float gg = Ra[2][j] + Ga[j].z, go = Ra[3][j] + Ga[j].w;
            csa[j] = sigf(gf)*csa[j] + sigf(gi)*tanhfast(gg);
            float h = sigf(go)*tanhfast(csa[j]);
            Hh[m0 + j][ua] = (f16)h;
            if (tt == 15) {
                int word = mb + m0 + j, bb = word >> 8, ss = word & 255;
                float mk = (ss < word_num[bb]) ? 1.f : 0.f;
                wfbuf[(size_t)word*152 + 100 + dir*25 + ua] = h*mk;
            }
        }
        if (hasb) {
#pragma unroll
            for (int j = 0; j < 4; ++j) {
                float gi = Rb[0][j] + Gb[j].x, gf = Rb[1][j] + Gb[j].y;
                float gg = Rb[2][j] + Gb[j].z, go = Rb[3][j] + Gb[j].w;
                csb[j] = sigf(gf)*csb[j] + sigf(gi)*tanhfast(gg);
                float h = sigf(go)*tanhfast(csb[j]);
                Hh[m0 + j][ub] = (f16)h;
                if (tt == 15) {
                    int word = mb + m0 + j, bb = word >> 8, ss = word & 255;
                    float mk = (ss < word_num[bb]) ? 1.f : 0.f;
                    wfbuf[(size_t)word*152 + 100 + dir*25 + ub] = h*mk;
                }
            }
        }
        barrier_lds();
        if (tt < 15) {
#pragma unroll
            for (int j = 0; j < 4; ++j) { Ga[j] = Na[j]; Gb[j] = Nb[j]; }
        }
    }
}

// ---- K3: word input gates GEMM on MFMA, embedding gather fused into A-staging.
__global__ __launch_bounds__(256)
void k_gemm_mfma(
        const float* __restrict__ wfbuf, const float* __restrict__ we,
        const int* __restrict__ wids, const unsigned short* __restrict__ frag,
        const float* __restrict__ bc, __hip_bfloat16* __restrict__ gates) {
    __shared__ __align__(16) unsigned short As[64*168];   // 21504 B
    int mt  = blockIdx.x >> 1, dir = blockIdx.x & 1;
    int m0  = mt * 64;
    int tid = threadIdx.x;
    int wv  = tid >> 6;
    int lane = tid & 63;
    int lm  = lane & 15;
    int lg  = lane >> 4;
    {
        int row = tid >> 2, qc = tid & 3;
        const float* embp = we + (size_t)wids[m0 + row]*100;
        const float* chp  = wfbuf + (size_t)(m0 + row)*152;
        unsigned* dst = (unsigned*)As + row*84 + qc*19;
#pragma unroll
        for (int i = 0; i < 19; ++i) {
            int c = qc*38 + 2*i;     // even; emb/char boundary (100) never straddled
            float2 v;
            if (c < 100)       v = *(const float2*)&embp[c];
            else if (c < 150)  v = *(const float2*)&chp[c];
            else               v = make_float2(0.f, 0.f);
            dst[i] = ((unsigned)f2bf(v.y) << 16) | f2bf(v.x);
        }
        if (qc == 3) {   // zero k-pad cols 152..159
            unsigned* z = (unsigned*)As + row*84 + 76;
            z[0] = 0; z[1] = 0; z[2] = 0; z[3] = 0;
        }
    }
    __syncthreads();
    f32x4 acc[7][4] = {};
    const unsigned short* fb = frag + (size_t)dir*(5*25*512);
#pragma unroll
    for (int kc = 0; kc < 5; ++kc) {
        bf16x8 bfr[7];
#pragma unroll
        for (int j = 0; j < 7; ++j) {
            int nt = wv + 4*j;
            bf16x8 v = {};
            if (nt < 25)
                v = *(const bf16x8*)&fb[((size_t)(kc*25 + nt)*64 + lane)*8];
            bfr[j] = v;
        }
        bf16x8 afr[4];
#pragma unroll
        for (int mf = 0; mf < 4; ++mf)
            afr[mf] = *(const bf16x8*)&As[(mf*16 + lm)*168 + kc*32 + lg*8];
#pragma unroll
        for (int j = 0; j < 7; ++j) {
            int nt = wv + 4*j;
            if (nt < 25) {
#pragma unroll
                for (int mf = 0; mf < 4; ++mf)
                    acc[j][mf] = __builtin_amdgcn_mfma_f32_16x16x32_bf16(
                        afr[mf], bfr[j], acc[j][mf], 0, 0, 0);
            }
        }
    }
#pragma unroll
    for (int j = 0; j < 7; ++j) {
        int nt = wv + 4*j;
        if (nt >= 25) continue;
        int n = nt*16 + lm;
        float bias = bc[dir*400 + n];
        int u = n % 100, g = n / 100;
#pragma unroll
        for (int mf = 0; mf < 4; ++mf) {
#pragma unroll
            for (int r = 0; r < 4; ++r) {
                int m = m0 + mf*16 + lg*4 + r;
                gates[((size_t)dir*TOK + m)*400 + u*4 + g]
                    = __float2bfloat16(acc[j][mf][r] + bias);
            }
        }
    }
}

// ---- K4: word BiLSTM — dot2, 512 threads, waves_per_eu(2,2), 88 VGPR.
//      PERMANENTLY FROZEN at ~200 µs (structural floor; see r10/r13/r14 notes).
__global__ __launch_bounds__(512)
__attribute__((amdgpu_waves_per_eu(2, 2)))
void k_word(
        const __hip_bfloat16* __restrict__ gates,
        const float* __restrict__ whh_f, const float* __restrict__ whh_b,
        __hip_bfloat16* __restrict__ wh) {
    int b = blockIdx.x >> 1, dir = blockIdx.x & 1;
    int tid = threadIdx.x;
    int wv   = tid >> 6;            // wave 0..7
    int lane = tid & 63;
    int q    = lane >> 4;           // k-quarter: contiguous k in [q*26, q*26+26)
    int u    = wv*16 + (lane & 15); // unit 0..127
    bool act = (u < 100);
    const float* whh = dir ? whh_b : whh_f;
    __shared__ __align__(16) uint32_t Hs[2][64];
    for (int i = tid; i < 128; i += 512) ((uint32_t*)Hs)[i] = 0;
    f16x2 W[4][13];
#pragma unroll
    for (int gi = 0; gi < 4; ++gi)
#pragma unroll
        for (int i = 0; i < 13; ++i) {
            int k0 = q*26 + 2*i;
            f16x2 v = {};
            if (act) {
                const float* r = &whh[(size_t)(gi*100 + u)*100];
                if (k0 < 100)     v.x = (f16)r[k0];
                if (k0 + 1 < 100) v.y = (f16)r[k0+1];
            }
            W[gi][i] = v;
        }
    int hq = u / 26, hr = u - hq*26;
    int hwofs = hq*32 + hr;     // ushort index into Hs[buf]
    float cst = 0.f;
    const unsigned short* gp = (const unsigned short*)gates
                             + (size_t)(dir*TOK + b*256)*400;   // [t][u*4+gate]
    __syncthreads();
    int t0 = dir ? 255 : 0;
    ushort4 Gc = *(const ushort4*)(gp + (size_t)t0*400 + (act ? u*4 : 0));
    ushort4 Gn = Gc;
#pragma unroll 1
    for (int tt = 0; tt < 256; ++tt) {
        int t = dir ? (255 - tt) : tt;
        if (tt < 255) {
            int tn = dir ? (t - 1) : (t + 1);
            Gn = *(const ushort4*)(gp + (size_t)tn*400 + (act ? u*4 : 0));
        }
        const uint32_t* hb = Hs[tt & 1] + q*16;
        const uint4* hp4 = (const uint4*)hb;
        uint4 hA = hp4[0], hB = hp4[1], hC = hp4[2];
        uint32_t hD = hb[12];
        uint32_t hw[13] = {hA.x, hA.y, hA.z, hA.w,
                           hB.x, hB.y, hB.z, hB.w,
                           hC.x, hC.y, hC.z, hC.w, hD};
        float a0 = 0.f, a1 = 0.f, a2 = 0.f, a3 = 0.f;
#pragma unroll
        for (int i = 0; i < 13; ++i) {
            f16x2 h2 = u2h2(hw[i]);
            a0 = dot2(W[0][i], h2, a0);
            a1 = dot2(W[1][i], h2, a1);
            a2 = dot2(W[2][i], h2, a2);
            a3 = dot2(W[3][i], h2, a3);
        }
        a0 += __shfl_xor(a0, 16, 64); a0 += __shfl_xor(a0, 32, 64);
        a1 += __shfl_xor(a1, 16, 64); a1 += __shfl_xor(a1, 32, 64);
        a2 += __shfl_xor(a2, 16, 64); a2 += __shfl_xor(a2, 32, 64);
        a3 += __shfl_xor(a3, 16, 64); a3 += __shfl_xor(a3, 32, 64);
        float gI = bf2f(Gc.x) + a0, gF = bf2f(Gc.y) + a1;
        float gG = bf2f(Gc.z) + a2, gO = bf2f(Gc.w) + a3;
        cst = sigf(gF)*cst + sigf(gI)*tanhfast(gG);
        float h = sigf(gO)*tanhfast(cst);
        if (act && q == 0) {
            union { f16 hh; unsigned short us; } cv; cv.hh = (f16)h;
            ((unsigned short*)Hs[(tt + 1) & 1])[hwofs] = cv.us;
            wh[(size_t)(b*256 + t)*200 + dir*100 + u] = __float2bfloat16(h);
        }
        barrier_lds();   // LDS-only: prefetch + wh stores stay in flight
        Gc = Gn;
    }
}

// ---- K5: feats on MFMA (proven round 12).
__global__ __launch_bounds__(256) void k_feats(
        const __hip_bfloat16* __restrict__ wh, const unsigned short* __restrict__ frag,
        const float* __restrict__ b1, const float* __restrict__ W2,
        const float* __restrict__ b2, const int* __restrict__ word_num,
        float* __restrict__ feats) {
    __shared__ __align__(16) char smem[29696];   // As [64][232]bf16 = 29696 B
    unsigned short* As = (unsigned short*)smem;  // row stride 232 bf16 (116 dwords)
    float* mids = (float*)smem;                  // later: [64][108] f32 = 27648 B
    int m0  = blockIdx.x * 64;
    int tid = threadIdx.x;
    int wv  = tid >> 6;
    int lane = tid & 63;
    int lm  = lane & 15;
    int lg  = lane >> 4;
    {
        int row = tid >> 2, qc = tid & 3;
        const uint32_t* src = (const uint32_t*)(wh + (size_t)(m0 + row)*200);
        uint32_t* dst = (uint32_t*)As + row*116 + qc*28;
#pragma unroll
        for (int i = 0; i < 28; ++i) {
            int d = qc*28 + i;
            dst[i] = (d < 100) ? src[d] : 0u;
        }
    }
    __syncthreads();
    f32x4 acc[2][4] = {};
#pragma unroll
    for (int kc = 0; kc < 7; ++kc) {
        bf16x8 bfr[2];
#pragma unroll
        for (int j = 0; j < 2; ++j) {
            int nt = wv + 4*j;
            bf16x8 v = {};
            if (nt < 7)
                v = *(const bf16x8*)&frag[((size_t)(kc*7 + nt)*64 + lane)*8];
            bfr[j] = v;
        }
        bf16x8 afr[4];
#pragma unroll
        for (int mf = 0; mf < 4; ++mf)
            afr[mf] = *(const bf16x8*)&As[(mf*16 + lm)*232 + kc*32 + lg*8];
#pragma unroll
        for (int j = 0; j < 2; ++j) {
            int nt = wv + 4*j;
            if (nt < 7) {
#pragma unroll
                for (int mf = 0; mf < 4; ++mf)
                    acc[j][mf] = __builtin_amdgcn_mfma_f32_16x16x32_bf16(
                        afr[mf], bfr[j], acc[j][mf], 0, 0, 0);
            }
        }
    }
    __syncthreads();   // As dead; smem becomes mids
#pragma unroll
    for (int j = 0; j < 2; ++j) {
        int nt = wv + 4*j;
        if (nt >= 7) continue;
        int n = nt*16 + lm;
        if (n >= 100) continue;
        float b1v = b1[n];
#pragma unroll
        for (int mf = 0; mf < 4; ++mf) {
#pragma unroll
            for (int r = 0; r < 4; ++r)
                mids[(mf*16 + lg*4 + r)*108 + n] = tanhfast(acc[j][mf][r] + b1v);
        }
    }
    __syncthreads();
    for (int idx = tid; idx < 576; idx += 256) {
        int tok = idx / 9, lab = idx - tok*9;
        int m = m0 + tok, bb = m >> 8, s = m & 255;
        float v = b2[lab];
        const f32x4* mp = (const f32x4*)&mids[tok*108];
        const float4* wp = (const float4*)(W2 + lab*100);
#pragma unroll
        for (int k = 0; k < 25; ++k) {
            f32x4 mv = mp[k];
            float4 wv4 = wp[k];
            v += mv[0]*wv4.x + mv[1]*wv4.y + mv[2]*wv4.z + mv[3]*wv4.w;
        }
        feats[(size_t)m*12 + lab] = (s < word_num[bb]) ? v : 0.f;
    }
}

// ---- K6: CRF. v2: obs(t+1) register-prefetched BEFORE step t's shuffle chain
//      (the in-loop fb load exposed ~200-400 cyc of L2/L3 latency per step on a
//      lone wave), and the 11-deep sequential fmax/add chains hand-treed to
//      4-deep (compiler can't reassociate FP). Same math, same precision.
__global__ __launch_bounds__(64) void k_crf(
        const float* __restrict__ feats, const float* __restrict__ T,
        const int* __restrict__ word_num, const int* __restrict__ label_ids,
        float* __restrict__ perb) {
    int b = blockIdx.x, lane = threadIdx.x;
    int n = word_num[b];
    const int*   lab = label_ids + b*256;
    const float* fb  = feats + (size_t)b*256*12;
    float nm = 0.f;
    for (int t = lane; t < n; t += 64) {
        int lt = lab[t];
        int lp = (t == 0) ? 9 : lab[t-1];
        nm += fb[t*12 + lt] + T[lp*11 + lt];
    }
#pragma unroll
    for (int o = 32; o > 0; o >>= 1) nm += __shfl_down(nm, o, 64);
    nm = __shfl(nm, 0, 64);
    nm += T[lab[n-1]*11 + 10];
    int j = lane;
    float Tc[11];
#pragma unroll
    for (int i = 0; i < 11; ++i) Tc[i] = T[i*11 + (j < 11 ? j : 0)];
    float alpha = (j == 9) ? 0.f : -1000.f;
    float obs = (j < 9) ? fb[j] : -1000.f;      // t = 0 (n >= 1 guaranteed)
    for (int t = 0; t < n; ++t) {
        // prefetch next step's obs: load issues before the shuffle chain and
        // its latency hides under it
        float obs_n = -1000.f;
        if (t + 1 < n && j < 9) obs_n = fb[(t+1)*12 + j];
        float v[11];
#pragma unroll
        for (int i = 0; i < 11; ++i) v[i] = __shfl(alpha, i, 64) + Tc[i];
        // tree max (4-deep)
        float m01 = fmaxf(v[0], v[1]), m23 = fmaxf(v[2], v[3]);
        float m45 = fmaxf(v[4], v[5]), m67 = fmaxf(v[6], v[7]);
        float m89 = fmaxf(v[8], v[9]);
        float mA = fmaxf(m01, m23), mB = fmaxf(m45, m67), mC = fmaxf(m89, v[10]);
        float mx = fmaxf(fmaxf(mA, mB), mC);
        // tree sum of exps
        float e0 = __expf(v[0]-mx), e1 = __expf(v[1]-mx), e2 = __expf(v[2]-mx);
        float e3 = __expf(v[3]-mx), e4 = __expf(v[4]-mx), e5 = __expf(v[5]-mx);
        float e6 = __expf(v[6]-mx), e7 = __expf(v[7]-mx), e8 = __expf(v[8]-mx);
        float e9 = __expf(v[9]-mx), e10 = __expf(v[10]-mx);
        float s01 = e0+e1, s23 = e2+e3, s45 = e4+e5, s67 = e6+e7, s89 = e8+e9;
        float sA = s01+s23, sB = s45+s67, sC = s89+e10;
        float ssum = (sA+sB) + sC;
        alpha = obs + mx + __logf(ssum);
        obs = obs_n;
    }
    float vv[11];
#pragma unroll
    for (int i = 0; i < 11; ++i) vv[i] = __shfl(alpha, i, 64) + Tc[i];
    float m01 = fmaxf(vv[0], vv[1]), m23 = fmaxf(vv[2], vv[3]);
    float m45 = fmaxf(vv[4], vv[5]), m67 = fmaxf(vv[6], vv[7]);
    float m89 = fmaxf(vv[8], vv[9]);
    float mx = fmaxf(fmaxf(fmaxf(m01, m23), fmaxf(m45, m67)), fmaxf(m89, vv[10]));
    float ssum = 0.f;
#pragma unroll
    for (int i = 0; i < 11; ++i) ssum += __expf(vv[i] - mx);
    float denom = __shfl(mx + __logf(ssum), 10, 64);
    if (lane == 0) perb[b] = denom - nm;
}

// ---- K7: mean over batch
__global__ void k_reduce(const float* __restrict__ perb, float* __restrict__ out) {
    int t = threadIdx.x;
    float v = perb[t];
#pragma unroll
    for (int o = 32; o > 0; o >>= 1) v += __shfl_down(v, o, 64);
    __shared__ float sm[2];
    if ((t & 63) == 0) sm[t >> 6] = v;
    __syncthreads();
    if (t == 0) out[0] = (sm[0] + sm[1]) * (1.0f/128.0f);
}

extern "C" void kernel_launch(void* const* d_in, const int* in_sizes, int n_in,
                              void* d_out, int out_size, void* d_ws, size_t ws_size,
                              hipStream_t stream) {
    const float* word_emb = (const float*)d_in[0];
    const float* char_emb = (const float*)d_in[1];
    const float* cWih_f   = (const float*)d_in[2];
    const float* cWhh_f   = (const float*)d_in[3];
    const float* cb_f     = (const float*)d_in[4];
    const float* cWih_b   = (const float*)d_in[5];
    const float* cWhh_b   = (const float*)d_in[6];
    const float* cb_b     = (const float*)d_in[7];
    const float* wWih_f   = (const float*)d_in[8];
    const float* wWhh_f   = (const float*)d_in[9];
    const float* wb_f     = (const float*)d_in[10];
    const float* wWih_b   = (const float*)d_in[11];
    const float* wWhh_b   = (const float*)d_in[12];
    const float* wb_b     = (const float*)d_in[13];
    const float* W1       = (const float*)d_in[14];
    const float* b1       = (const float*)d_in[15];
    const float* W2       = (const float*)d_in[16];
    const float* b2       = (const float*)d_in[17];
    const float* T        = (const float*)d_in[18];
    const int* word_num   = (const int*)d_in[19];
    const int* word_ids   = (const int*)d_in[20];
    const int* char_ids   = (const int*)d_in[21];
    const int* label_ids  = (const int*)d_in[22];

    char* ws = (char*)d_ws;
    float* gin            = (float*)(ws);                       //    80,000 B
    unsigned short* ffrag = (unsigned short*)(ws + 80000);      //    50,176 B (own slot now)
    float* bc             = (float*)(ws + 566400);              //     3,200 B
    float* wfbuf          = (float*)(ws + 569600);              // 19,922,944 B [32768][152] (cols 100..149 used)
    __hip_bfloat16* gates = (__hip_bfloat16*)(ws + 20492544);   // 52,428,800 B [2][32768][400]
    __hip_bfloat16* wh    = (__hip_bfloat16*)(ws + 72921344);   // 13,107,200 B [32768][200]
    float* feats          = (float*)(ws + 86028544);            //  1,572,864 B [32768][12]
    float* perb           = (float*)(ws + 87601408);            //       512 B
    // cfrag (14,336 B) aliases head of `gates`: k_prep -> k_char reads ->
    // overwritten by k_gemm_mfma (strictly serial).
    unsigned short* cfrag = (unsigned short*)(ws + 20492544);
    // wfrag (256,000 B) aliases head of `wh`: k_prep -> k_gemm_mfma -> k_word
    // overwrites wh (serial).
    unsigned short* wfrag = (unsigned short*)(ws + 72921344);

    k_prep  <<<377, 256, 0, stream>>>(char_emb, cWih_f, cb_f, cWih_b, cb_b,
                                      wWih_f, wb_f, wWih_b, wb_b,
                                      cWhh_f, cWhh_b, W1,
                                      gin, wfrag, bc, cfrag, ffrag);
    k_char  <<<1024, 256, 0, stream>>>(cfrag, gin, char_ids, word_num, wfbuf);
    k_gemm_mfma<<<1024, 256, 0, stream>>>(wfbuf, word_emb, word_ids, wfrag, bc, gates);
    k_word  <<<256, 512, 0, stream>>>(gates, wWhh_f, wWhh_b, wh);
    k_feats <<<512, 256, 0, stream>>>(wh, ffrag, b1, W2, b2, word_num, feats);
    k_crf   <<<128, 64, 0, stream>>>(feats, T, word_num, label_ids, perb);
    k_reduce<<<1, 128, 0, stream>>>(perb, (float*)d_out);
}

// Round 18
// 503.881 us; speedup vs baseline: 1.2654x; 1.0379x over previous
//
#include <hip/hip_runtime.h>
#include <hip/hip_bf16.h>
#include <cstdint>
#include <cstddef>

#define B_ 128
#define S_ 256
#define TOK (B_*S_)   // 32768

typedef _Float16 f16;
typedef _Float16 f16x2 __attribute__((ext_vector_type(2)));
typedef _Float16 half8 __attribute__((ext_vector_type(8)));
typedef __bf16 bf16x8 __attribute__((ext_vector_type(8)));
typedef float  f32x4  __attribute__((ext_vector_type(4)));

__device__ __forceinline__ float sigf(float x) {
    return __builtin_amdgcn_rcpf(1.0f + __expf(-x));
}
__device__ __forceinline__ float tanhfast(float x) {
    return 1.0f - 2.0f * __builtin_amdgcn_rcpf(1.0f + __expf(2.0f * x));
}
__device__ __forceinline__ float bf2f(unsigned short v) {
    union { unsigned u; float f; } c; c.u = ((unsigned)v) << 16; return c.f;
}
__device__ __forceinline__ unsigned short f2bf(float f) {
    return (unsigned short)(__bfloat16_as_ushort(__float2bfloat16(f)));
}
// packed f16 dot2 with f32 accumulate (VOP3P)
__device__ __forceinline__ float dot2(f16x2 a, f16x2 b, float c) {
    float d;
    asm("v_dot2_f32_f16 %0, %1, %2, %3" : "=v"(d) : "v"(a), "v"(b), "v"(c));
    return d;
}
__device__ __forceinline__ f16x2 u2h2(uint32_t v) {
    union { uint32_t u; f16x2 h; } c; c.u = v; return c.h;
}
// LDS-only barrier: skips __syncthreads' implicit vmcnt(0) so in-flight global
// loads (prefetches) and stores survive across the barrier.
__device__ __forceinline__ void barrier_lds() {
    asm volatile("s_waitcnt lgkmcnt(0)\n\ts_barrier" ::: "memory");
}

// ---- K1: fused prep — one launch, blocks dispatch by range:
//      blk 0..7     : gin quads, c-chunks of 13 (v2: was ONE serial block ~8-10 µs
//                     gating k_char; now ~1.3 µs)
//      blk 8..257   : word-Wih bf16 fragments + bias (64000 elems)
//      blk 258..285 : char-Whh f16 fragments (7168)
//      blk 286..383 : W1 bf16 fragments (25088)
__global__ __launch_bounds__(256) void k_prep(
        const float* __restrict__ ce,
        const float* __restrict__ cWih_f, const float* __restrict__ cb_f,
        const float* __restrict__ cWih_b, const float* __restrict__ cb_b,
        const float* __restrict__ wWih_f, const float* __restrict__ wb_f,
        const float* __restrict__ wWih_b, const float* __restrict__ wb_b,
        const float* __restrict__ cWhh_f, const float* __restrict__ cWhh_b,
        const float* __restrict__ W1,
        float* __restrict__ gin, unsigned short* __restrict__ wfrag,
        float* __restrict__ bc, unsigned short* __restrict__ cfrag,
        unsigned short* __restrict__ ffrag) {
    int blk = blockIdx.x, tid = threadIdx.x;
    if (blk < 8) {
        // gin[(dir*100+c)*100 + u*4+g] = b + Wih·emb (row = g*25+u)
        if (tid < 200) {
            int dir = tid / 100, row = tid % 100;
            int g = row / 25, u = row - g*25;
            const float* wih = dir ? cWih_b : cWih_f;
            float bias = dir ? cb_b[row] : cb_f[row];
            int c0 = blk*13, c1 = min(100, c0 + 13);
            for (int c = c0; c < c1; ++c) {
                float s = bias;
#pragma unroll
                for (int k = 0; k < 25; ++k) s += wih[row*25 + k] * ce[c*25 + k];
                gin[(dir*100 + c)*100 + u*4 + g] = s;
            }
        }
    } else if (blk < 258) {
        int idx = (blk - 8)*256 + tid;          // 0..63999
        if (idx < 2*5*25*512) {
            int e  = idx & 7;
            int l  = (idx >> 3) & 63;
            int r  = idx >> 9;
            int nt = r % 25;
            int r2 = r / 25;
            int kc = r2 % 5;
            int d  = r2 / 5;
            int k  = kc*32 + (l >> 4)*8 + e;
            int nl = nt*16 + (l & 15);
            const float* w = d ? wWih_b : wWih_f;
            float v = (k < 150) ? w[nl*150 + k] : 0.f;
            wfrag[idx] = f2bf(v);
        }
        if (idx < 800) {
            int d = idx >= 400 ? 1 : 0, r = idx - d*400;
            bc[idx] = d ? wb_b[r] : wb_f[r];
        }
    } else if (blk < 286) {
        int idx = (blk - 258)*256 + tid;        // 0..7167
        if (idx < 2*7*64*8) {
            int e  = idx & 7;
            int l  = (idx >> 3) & 63;
            int r  = idx >> 9;
            int nt = r % 7;
            int d  = r / 7;
            int k  = (l >> 4)*8 + e;
            int n  = nt*16 + (l & 15);
            const float* w = d ? cWhh_b : cWhh_f;
            float v = (n < 100 && k < 25) ? w[n*25 + k] : 0.f;
            union { f16 h; unsigned short s; } c; c.h = (f16)v;
            cfrag[idx] = c.s;
        }
    } else {
        int idx = (blk - 286)*256 + tid;        // 0..25087
        if (idx < 7*7*512) {
            int e  = idx & 7;
            int l  = (idx >> 3) & 63;
            int r  = idx >> 9;
            int nt = r % 7;
            int kc = r / 7;
            int k  = kc*32 + (l >> 4)*8 + e;
            int n  = nt*16 + (l & 15);
            float v = (n < 100 && k < 200) ? W1[(size_t)n*200 + k] : 0.f;
            ffrag[idx] = f2bf(v);
        }
    }
}

// ---- K2: char BiLSTM on MFMA (proven round 9).
__global__ __launch_bounds__(256)
void k_char(
        const unsigned short* __restrict__ cfrag, const float* __restrict__ gin,
        const int* __restrict__ char_ids, const int* __restrict__ word_num,
        float* __restrict__ wfbuf) {
    __shared__ __align__(16) f16  Hh[64][40];    // h state, row stride 40 (16B-aligned)
    __shared__ __align__(16) float Ct[100][68];  // C^T: [gate*25+u][word]
    __shared__ int chlT[16][64];                 // char ids transposed [t][word]
    int wt = blockIdx.x >> 1, dir = blockIdx.x & 1;
    int mb = wt*64;
    int tid = threadIdx.x;
    int wv = tid >> 6, lane = tid & 63, lm = lane & 15, lg = lane >> 4;
    int nt0 = wv, nt1 = wv + 4;
    const f16* cf = (const f16*)cfrag;
    half8 B0 = *(const half8*)&cf[((dir*7 + nt0)*64 + lane)*8];
    half8 B1 = {};
    if (nt1 < 7) B1 = *(const half8*)&cf[((dir*7 + nt1)*64 + lane)*8];
    {
        int w = tid >> 2, j4 = tid & 3;
        int4 v = *(const int4*)&char_ids[(size_t)(mb + w)*16 + j4*4];
        chlT[j4*4+0][w] = v.x; chlT[j4*4+1][w] = v.y;
        chlT[j4*4+2][w] = v.z; chlT[j4*4+3][w] = v.w;
    }
    for (int i = tid; i < 1280; i += 256) ((uint32_t*)Hh)[i] = 0;   // h0=0 + pad
    __syncthreads();
    int ua = tid >> 4;            // 0..15
    int ub = ua + 16;             // valid if <25
    bool hasb = (ub < 25);
    int m0 = (tid & 15)*4;
    float csa[4] = {0,0,0,0}, csb[4] = {0,0,0,0};
    const float* ginD = gin + dir*100*100;
    f32x4 zz = {0.f, 0.f, 0.f, 0.f};
    int t0 = dir ? 15 : 0;
    float4 Ga[4], Gb[4], Na[4], Nb[4];
#pragma unroll
    for (int j = 0; j < 4; ++j) {
        int c = chlT[t0][m0 + j];
        Ga[j] = *(const float4*)&ginD[c*100 + ua*4];
        Gb[j] = hasb ? *(const float4*)&ginD[c*100 + ub*4] : make_float4(0,0,0,0);
    }
#pragma unroll 1
    for (int tt = 0; tt < 16; ++tt) {
        f32x4 a0[4], a1[4];
#pragma unroll
        for (int mf = 0; mf < 4; ++mf) {
            half8 A = *(const half8*)&Hh[mf*16 + lm][lg*8];
            a0[mf] = __builtin_amdgcn_mfma_f32_16x16x32_f16(A, B0, zz, 0, 0, 0);
            a1[mf] = (nt1 < 7)
                ? __builtin_amdgcn_mfma_f32_16x16x32_f16(A, B1, zz, 0, 0, 0) : zz;
        }
#pragma unroll
        for (int mf = 0; mf < 4; ++mf) {
            *(f32x4*)&Ct[nt0*16 + lm][mf*16 + lg*4] = a0[mf];
            if (nt1 < 7 && nt1*16 + lm < 100)
                *(f32x4*)&Ct[nt1*16 + lm][mf*16 + lg*4] = a1[mf];
        }
        if (tt < 15) {
            int tn = dir ? (14 - tt) : (tt + 1);
            int4 cs4 = *(const int4*)&chlT[tn][m0];
            int cj[4] = {cs4.x, cs4.y, cs4.z, cs4.w};
#pragma unroll
            for (int j = 0; j < 4; ++j) {
                Na[j] = *(const float4*)&ginD[cj[j]*100 + ua*4];
                Nb[j] = hasb ? *(const float4*)&ginD[cj[j]*100 + ub*4]
                             : make_float4(0,0,0,0);
            }
        }
        barrier_lds();
        f32x4 Ra[4], Rb[4];
#pragma unroll
        for (int g = 0; g < 4; ++g) {
            Ra[g] = *(const f32x4*)&Ct[g*25 + ua][m0];
            if (hasb) Rb[g] = *(const f32x4*)&Ct[g*25 + ub][m0];
        }
#pragma unroll
        for (int j = 0; j < 4; ++j) {
            float gi = Ra[0][j] + Ga[j].x, gf = Ra[1][j] + Ga[j].y;
            float gg = Ra[2][j] + Ga[j].z, go = Ra[3][j] + Ga[j].w;
            csa[j] = sigf(gf)*csa[j] + sigf(gi)*tanhfast(gg);
            float h = sigf(go)*tanhfast(csa[j]);
            Hh[m0 + j][ua] = (f16)h;
            if (tt == 15) {
                int word = mb + m0 + j, bb = word >> 8, ss = word & 255;
                float mk = (ss < word_num[bb]) ? 1.f : 0.f;
                wfbuf[(size_t)word*152 + 100 + dir*25 + ua] = h*mk;
            }
        }
        if (hasb) {
#pragma unroll
            for (int j = 0; j < 4; ++j) {
                float gi = Rb[0][j] + Gb[j].x, gf = Rb[1][j] + Gb[j].y;
                float gg = Rb[2][j] + Gb[j].z, go = Rb[3][j] + Gb[j].w;
                csb[j] = sigf(gf)*csb[j] + sigf(gi)*tanhfast(gg);
                float h = sigf(go)*tanhfast(csb[j]);
                Hh[m0 + j][ub] = (f16)h;
                if (tt == 15) {
                    int word = mb + m0 + j, bb = word >> 8, ss = word & 255;
                    float mk = (ss < word_num[bb]) ? 1.f : 0.f;
                    wfbuf[(size_t)word*152 + 100 + dir*25 + ub] = h*mk;
                }
            }
        }
        barrier_lds();
        if (tt < 15) {
#pragma unroll
            for (int j = 0; j < 4; ++j) { Ga[j] = Na[j]; Gb[j] = Nb[j]; }
        }
    }
}

// ---- K3: word input gates GEMM on MFMA, embedding gather fused into A-staging.
__global__ __launch_bounds__(256)
void k_gemm_mfma(
        const float* __restrict__ wfbuf, const float* __restrict__ we,
        const int* __restrict__ wids, const unsigned short* __restrict__ frag,
        const float* __restrict__ bc, __hip_bfloat16* __restrict__ gates) {
    __shared__ __align__(16) unsigned short As[64*168];   // 21504 B
    int mt  = blockIdx.x >> 1, dir = blockIdx.x & 1;
    int m0  = mt * 64;
    int tid = threadIdx.x;
    int wv  = tid >> 6;
    int lane = tid & 63;
    int lm  = lane & 15;
    int lg  = lane >> 4;
    {
        int row = tid >> 2, qc = tid & 3;
        const float* embp = we + (size_t)wids[m0 + row]*100;
        const float* chp  = wfbuf + (size_t)(m0 + row)*152;
        unsigned* dst = (unsigned*)As + row*84 + qc*19;
#pragma unroll
        for (int i = 0; i < 19; ++i) {
            int c = qc*38 + 2*i;     // even; emb/char boundary (100) never straddled
            float2 v;
            if (c < 100)       v = *(const float2*)&embp[c];
            else if (c < 150)  v = *(const float2*)&chp[c];
            else               v = make_float2(0.f, 0.f);
            dst[i] = ((unsigned)f2bf(v.y) << 16) | f2bf(v.x);
        }
        if (qc == 3) {   // zero k-pad cols 152..159
            unsigned* z = (unsigned*)As + row*84 + 76;
            z[0] = 0; z[1] = 0; z[2] = 0; z[3] = 0;
        }
    }
    __syncthreads();
    f32x4 acc[7][4] = {};
    const unsigned short* fb = frag + (size_t)dir*(5*25*512);
#pragma unroll
    for (int kc = 0; kc < 5; ++kc) {
        bf16x8 bfr[7];
#pragma unroll
        for (int j = 0; j < 7; ++j) {
            int nt = wv + 4*j;
            bf16x8 v = {};
            if (nt < 25)
                v = *(const bf16x8*)&fb[((size_t)(kc*25 + nt)*64 + lane)*8];
            bfr[j] = v;
        }
        bf16x8 afr[4];
#pragma unroll
        for (int mf = 0; mf < 4; ++mf)
            afr[mf] = *(const bf16x8*)&As[(mf*16 + lm)*168 + kc*32 + lg*8];
#pragma unroll
        for (int j = 0; j < 7; ++j) {
            int nt = wv + 4*j;
            if (nt < 25) {
#pragma unroll
                for (int mf = 0; mf < 4; ++mf)
                    acc[j][mf] = __builtin_amdgcn_mfma_f32_16x16x32_bf16(
                        afr[mf], bfr[j], acc[j][mf], 0, 0, 0);
            }
        }
    }
#pragma unroll
    for (int j = 0; j < 7; ++j) {
        int nt = wv + 4*j;
        if (nt >= 25) continue;
        int n = nt*16 + lm;
        float bias = bc[dir*400 + n];
        int u = n % 100, g = n / 100;
#pragma unroll
        for (int mf = 0; mf < 4; ++mf) {
#pragma unroll
            for (int r = 0; r < 4; ++r) {
                int m = m0 + mf*16 + lg*4 + r;
                gates[((size_t)dir*TOK + m)*400 + u*4 + g]
                    = __float2bfloat16(acc[j][mf][r] + bias);
            }
        }
    }
}

// ---- K4: word BiLSTM — dot2, 512 threads, waves_per_eu(2,2), 88 VGPR.
//      PERMANENTLY FROZEN at ~200 µs (structural floor; see r10/r13/r14 notes).
__global__ __launch_bounds__(512)
__attribute__((amdgpu_waves_per_eu(2, 2)))
void k_word(
        const __hip_bfloat16* __restrict__ gates,
        const float* __restrict__ whh_f, const float* __restrict__ whh_b,
        __hip_bfloat16* __restrict__ wh) {
    int b = blockIdx.x >> 1, dir = blockIdx.x & 1;
    int tid = threadIdx.x;
    int wv   = tid >> 6;            // wave 0..7
    int lane = tid & 63;
    int q    = lane >> 4;           // k-quarter: contiguous k in [q*26, q*26+26)
    int u    = wv*16 + (lane & 15); // unit 0..127
    bool act = (u < 100);
    const float* whh = dir ? whh_b : whh_f;
    __shared__ __align__(16) uint32_t Hs[2][64];
    for (int i = tid; i < 128; i += 512) ((uint32_t*)Hs)[i] = 0;
    f16x2 W[4][13];
#pragma unroll
    for (int gi = 0; gi < 4; ++gi)
#pragma unroll
        for (int i = 0; i < 13; ++i) {
            int k0 = q*26 + 2*i;
            f16x2 v = {};
            if (act) {
                const float* r = &whh[(size_t)(gi*100 + u)*100];
                if (k0 < 100)     v.x = (f16)r[k0];
                if (k0 + 1 < 100) v.y = (f16)r[k0+1];
            }
            W[gi][i] = v;
        }
    int hq = u / 26, hr = u - hq*26;
    int hwofs = hq*32 + hr;     // ushort index into Hs[buf]
    float cst = 0.f;
    const unsigned short* gp = (const unsigned short*)gates
                             + (size_t)(dir*TOK + b*256)*400;   // [t][u*4+gate]
    __syncthreads();
    int t0 = dir ? 255 : 0;
    ushort4 Gc = *(const ushort4*)(gp + (size_t)t0*400 + (act ? u*4 : 0));
    ushort4 Gn = Gc;
#pragma unroll 1
    for (int tt = 0; tt < 256; ++tt) {
        int t = dir ? (255 - tt) : tt;
        if (tt < 255) {
            int tn = dir ? (t - 1) : (t + 1);
            Gn = *(const ushort4*)(gp + (size_t)tn*400 + (act ? u*4 : 0));
        }
        const uint32_t* hb = Hs[tt & 1] + q*16;
        const uint4* hp4 = (const uint4*)hb;
        uint4 hA = hp4[0], hB = hp4[1], hC = hp4[2];
        uint32_t hD = hb[12];
        uint32_t hw[13] = {hA.x, hA.y, hA.z, hA.w,
                           hB.x, hB.y, hB.z, hB.w,
                           hC.x, hC.y, hC.z, hC.w, hD};
        float a0 = 0.f, a1 = 0.f, a2 = 0.f, a3 = 0.f;
#pragma unroll
        for (int i = 0; i < 13; ++i) {
            f16x2 h2 = u2h2(hw[i]);
            a0 = dot2(W[0][i], h2, a0);
            a1 = dot2(W[1][i], h2, a1);
            a2 = dot2(W[2][i], h2, a2);
            a3 = dot2(W[3][i], h2, a3);
        }
        a0 += __shfl_xor(a0, 16, 64); a0 += __shfl_xor(a0, 32, 64);
        a1 += __shfl_xor(a1, 16, 64); a1 += __shfl_xor(a1, 32, 64);
        a2 += __shfl_xor(a2, 16, 64); a2 += __shfl_xor(a2, 32, 64);
        a3 += __shfl_xor(a3, 16, 64); a3 += __shfl_xor(a3, 32, 64);
        float gI = bf2f(Gc.x) + a0, gF = bf2f(Gc.y) + a1;
        float gG = bf2f(Gc.z) + a2, gO = bf2f(Gc.w) + a3;
        cst = sigf(gF)*cst + sigf(gI)*tanhfast(gG);
        float h = sigf(gO)*tanhfast(cst);
        if (act && q == 0) {
            union { f16 hh; unsigned short us; } cv; cv.hh = (f16)h;
            ((unsigned short*)Hs[(tt + 1) & 1])[hwofs] = cv.us;
            wh[(size_t)(b*256 + t)*200 + dir*100 + u] = __float2bfloat16(h);
        }
        barrier_lds();   // LDS-only: prefetch + wh stores stay in flight
        Gc = Gn;
    }
}

// ---- K5: feats on MFMA (proven round 12). v2: block 0 also zeroes d_out so
//      k_crf can atomicAdd directly (k_reduce launch eliminated; stream order
//      guarantees feats completes before crf starts).
__global__ __launch_bounds__(256) void k_feats(
        const __hip_bfloat16* __restrict__ wh, const unsigned short* __restrict__ frag,
        const float* __restrict__ b1, const float* __restrict__ W2,
        const float* __restrict__ b2, const int* __restrict__ word_num,
        float* __restrict__ feats, float* __restrict__ out) {
    __shared__ __align__(16) char smem[29696];   // As [64][232]bf16 = 29696 B
    unsigned short* As = (unsigned short*)smem;  // row stride 232 bf16 (116 dwords)
    float* mids = (float*)smem;                  // later: [64][108] f32 = 27648 B
    int m0  = blockIdx.x * 64;
    int tid = threadIdx.x;
    if (blockIdx.x == 0 && tid == 0) out[0] = 0.f;
    int wv  = tid >> 6;
    int lane = tid & 63;
    int lm  = lane & 15;
    int lg  = lane >> 4;
    {
        int row = tid >> 2, qc = tid & 3;
        const uint32_t* src = (const uint32_t*)(wh + (size_t)(m0 + row)*200);
        uint32_t* dst = (uint32_t*)As + row*116 + qc*28;
#pragma unroll
        for (int i = 0; i < 28; ++i) {
            int d = qc*28 + i;
            dst[i] = (d < 100) ? src[d] : 0u;
        }
    }
    __syncthreads();
    f32x4 acc[2][4] = {};
#pragma unroll
    for (int kc = 0; kc < 7; ++kc) {
        bf16x8 bfr[2];
#pragma unroll
        for (int j = 0; j < 2; ++j) {
            int nt = wv + 4*j;
            bf16x8 v = {};
            if (nt < 7)
                v = *(const bf16x8*)&frag[((size_t)(kc*7 + nt)*64 + lane)*8];
            bfr[j] = v;
        }
        bf16x8 afr[4];
#pragma unroll
        for (int mf = 0; mf < 4; ++mf)
            afr[mf] = *(const bf16x8*)&As[(mf*16 + lm)*232 + kc*32 + lg*8];
#pragma unroll
        for (int j = 0; j < 2; ++j) {
            int nt = wv + 4*j;
            if (nt < 7) {
#pragma unroll
                for (int mf = 0; mf < 4; ++mf)
                    acc[j][mf] = __builtin_amdgcn_mfma_f32_16x16x32_bf16(
                        afr[mf], bfr[j], acc[j][mf], 0, 0, 0);
            }
        }
    }
    __syncthreads();   // As dead; smem becomes mids
#pragma unroll
    for (int j = 0; j < 2; ++j) {
        int nt = wv + 4*j;
        if (nt >= 7) continue;
        int n = nt*16 + lm;
        if (n >= 100) continue;
        float b1v = b1[n];
#pragma unroll
        for (int mf = 0; mf < 4; ++mf) {
#pragma unroll
            for (int r = 0; r < 4; ++r)
                mids[(mf*16 + lg*4 + r)*108 + n] = tanhfast(acc[j][mf][r] + b1v);
        }
    }
    __syncthreads();
    for (int idx = tid; idx < 576; idx += 256) {
        int tok = idx / 9, lab = idx - tok*9;
        int m = m0 + tok, bb = m >> 8, s = m & 255;
        float v = b2[lab];
        const f32x4* mp = (const f32x4*)&mids[tok*108];
        const float4* wp = (const float4*)(W2 + lab*100);
#pragma unroll
        for (int k = 0; k < 25; ++k) {
            f32x4 mv = mp[k];
            float4 wv4 = wp[k];
            v += mv[0]*wv4.x + mv[1]*wv4.y + mv[2]*wv4.z + mv[3]*wv4.w;
        }
        feats[(size_t)m*12 + lab] = (s < word_num[bb]) ? v : 0.f;
    }
}

// ---- K6: CRF (obs prefetch + tree reductions, proven round 16). v3: each block
//      atomicAdds its pre-scaled contribution into d_out (k_reduce eliminated;
//      d_out zeroed by k_feats, stream-ordered ahead).
__global__ __launch_bounds__(64) void k_crf(
        const float* __restrict__ feats, const float* __restrict__ T,
        const int* __restrict__ word_num, const int* __restrict__ label_ids,
        float* __restrict__ out) {
    int b = blockIdx.x, lane = threadIdx.x;
    int n = word_num[b];
    const int*   lab = label_ids + b*256;
    const float* fb  = feats + (size_t)b*256*12;
    float nm = 0.f;
    for (int t = lane; t < n; t += 64) {
        int lt = lab[t];
        int lp = (t == 0) ? 9 : lab[t-1];
        nm += fb[t*12 + lt] + T[lp*11 + lt];
    }
#pragma unroll
    for (int o = 32; o > 0; o >>= 1) nm += __shfl_down(nm, o, 64);
    nm = __shfl(nm, 0, 64);
    nm += T[lab[n-1]*11 + 10];
    int j = lane;
    float Tc[11];
#pragma unroll
    for (int i = 0; i < 11; ++i) Tc[i] = T[i*11 + (j < 11 ? j : 0)];
    float alpha = (j == 9) ? 0.f : -1000.f;
    float obs = (j < 9) ? fb[j] : -1000.f;      // t = 0 (n >= 1 guaranteed)
    for (int t = 0; t < n; ++t) {
        float obs_n = -1000.f;
        if (t + 1 < n && j < 9) obs_n = fb[(t+1)*12 + j];
        float v[11];
#pragma unroll
        for (int i = 0; i < 11; ++i) v[i] = __shfl(alpha, i, 64) + Tc[i];
        float m01 = fmaxf(v[0], v[1]), m23 = fmaxf(v[2], v[3]);
        float m45 = fmaxf(v[4], v[5]), m67 = fmaxf(v[6], v[7]);
        float m89 = fmaxf(v[8], v[9]);
        float mA = fmaxf(m01, m23), mB = fmaxf(m45, m67), mC = fmaxf(m89, v[10]);
        float mx = fmaxf(fmaxf(mA, mB), mC);
        float e0 = __expf(v[0]-mx), e1 = __expf(v[1]-mx), e2 = __expf(v[2]-mx);
        float e3 = __expf(v[3]-mx), e4 = __expf(v[4]-mx), e5 = __expf(v[5]-mx);
        float e6 = __expf(v[6]-mx), e7 = __expf(v[7]-mx), e8 = __expf(v[8]-mx);
        float e9 = __expf(v[9]-mx), e10 = __expf(v[10]-mx);
        float s01 = e0+e1, s23 = e2+e3, s45 = e4+e5, s67 = e6+e7, s89 = e8+e9;
        float sA = s01+s23, sB = s45+s67, sC = s89+e10;
        float ssum = (sA+sB) + sC;
        alpha = obs + mx + __logf(ssum);
        obs = obs_n;
    }
    float vv[11];
#pragma unroll
    for (int i = 0; i < 11; ++i) vv[i] = __shfl(alpha, i, 64) + Tc[i];
    float m01 = fmaxf(vv[0], vv[1]), m23 = fmaxf(vv[2], vv[3]);
    float m45 = fmaxf(vv[4], vv[5]), m67 = fmaxf(vv[6], vv[7]);
    float m89 = fmaxf(vv[8], vv[9]);
    float mx = fmaxf(fmaxf(fmaxf(m01, m23), fmaxf(m45, m67)), fmaxf(m89, vv[10]));
    float ssum = 0.f;
#pragma unroll
    for (int i = 0; i < 11; ++i) ssum += __expf(vv[i] - mx);
    float denom = __shfl(mx + __logf(ssum), 10, 64);
    if (lane == 0) atomicAdd(out, (denom - nm) * (1.0f/128.0f));
}

extern "C" void kernel_launch(void* const* d_in, const int* in_sizes, int n_in,
                              void* d_out, int out_size, void* d_ws, size_t ws_size,
                              hipStream_t stream) {
    const float* word_emb = (const float*)d_in[0];
    const float* char_emb = (const float*)d_in[1];
    const float* cWih_f   = (const float*)d_in[2];
    const float* cWhh_f   = (const float*)d_in[3];
    const float* cb_f     = (const float*)d_in[4];
    const float* cWih_b   = (const float*)d_in[5];
    const float* cWhh_b   = (const float*)d_in[6];
    const float* cb_b     = (const float*)d_in[7];
    const float* wWih_f   = (const float*)d_in[8];
    const float* wWhh_f   = (const float*)d_in[9];
    const float* wb_f     = (const float*)d_in[10];
    const float* wWih_b   = (const float*)d_in[11];
    const float* wWhh_b   = (const float*)d_in[12];
    const float* wb_b     = (const float*)d_in[13];
    const float* W1       = (const float*)d_in[14];
    const float* b1       = (const float*)d_in[15];
    const float* W2       = (const float*)d_in[16];
    const float* b2       = (const float*)d_in[17];
    const float* T        = (const float*)d_in[18];
    const int* word_num   = (const int*)d_in[19];
    const int* word_ids   = (const int*)d_in[20];
    const int* char_ids   = (const int*)d_in[21];
    const int* label_ids  = (const int*)d_in[22];

    char* ws = (char*)d_ws;
    float* gin            = (float*)(ws);                       //    80,000 B
    unsigned short* ffrag = (unsigned short*)(ws + 80000);      //    50,176 B
    float* bc             = (float*)(ws + 566400);              //     3,200 B
    float* wfbuf          = (float*)(ws + 569600);              // 19,922,944 B [32768][152] (cols 100..149 used)
    __hip_bfloat16* gates = (__hip_bfloat16*)(ws + 20492544);   // 52,428,800 B [2][32768][400]
    __hip_bfloat16* wh    = (__hip_bfloat16*)(ws + 72921344);   // 13,107,200 B [32768][200]
    float* feats          = (float*)(ws + 86028544);            //  1,572,864 B [32768][12]
    // cfrag (14,336 B) aliases head of `gates`: k_prep -> k_char reads ->
    // overwritten by k_gemm_mfma (strictly serial).
    unsigned short* cfrag = (unsigned short*)(ws + 20492544);
    // wfrag (256,000 B) aliases head of `wh`: k_prep -> k_gemm_mfma -> k_word
    // overwrites wh (serial).
    unsigned short* wfrag = (unsigned short*)(ws + 72921344);

    k_prep  <<<384, 256, 0, stream>>>(char_emb, cWih_f, cb_f, cWih_b, cb_b,
                                      wWih_f, wb_f, wWih_b, wb_b,
                                      cWhh_f, cWhh_b, W1,
                                      gin, wfrag, bc, cfrag, ffrag);
    k_char  <<<1024, 256, 0, stream>>>(cfrag, gin, char_ids, word_num, wfbuf);
    k_gemm_mfma<<<1024, 256, 0, stream>>>(wfbuf, word_emb, word_ids, wfrag, bc, gates);
    k_word  <<<256, 512, 0, stream>>>(gates, wWhh_f, wWhh_b, wh);
    k_feats <<<512, 256, 0, stream>>>(wh, ffrag, b1, W2, b2, word_num, feats, (float*)d_out);
    k_crf   <<<128, 64, 0, stream>>>(feats, T, word_num, label_ids, (float*)d_out);
}

// Round 19
// 481.817 us; speedup vs baseline: 1.3233x; 1.0458x over previous
//
#include <hip/hip_runtime.h>
#include <hip/hip_bf16.h>
#include <cstdint>
#include <cstddef>

#define B_ 128
#define S_ 256
#define TOK (B_*S_)   // 32768

typedef _Float16 f16;
typedef _Float16 f16x2 __attribute__((ext_vector_type(2)));
typedef _Float16 half8 __attribute__((ext_vector_type(8)));
typedef __bf16 bf16x8 __attribute__((ext_vector_type(8)));
typedef float  f32x4  __attribute__((ext_vector_type(4)));

__device__ __forceinline__ float sigf(float x) {
    return __builtin_amdgcn_rcpf(1.0f + __expf(-x));
}
__device__ __forceinline__ float tanhfast(float x) {
    return 1.0f - 2.0f * __builtin_amdgcn_rcpf(1.0f + __expf(2.0f * x));
}
__device__ __forceinline__ float bf2f(unsigned short v) {
    union { unsigned u; float f; } c; c.u = ((unsigned)v) << 16; return c.f;
}
__device__ __forceinline__ unsigned short f2bf(float f) {
    return (unsigned short)(__bfloat16_as_ushort(__float2bfloat16(f)));
}
// packed f16 dot2 with f32 accumulate (VOP3P)
__device__ __forceinline__ float dot2(f16x2 a, f16x2 b, float c) {
    float d;
    asm("v_dot2_f32_f16 %0, %1, %2, %3" : "=v"(d) : "v"(a), "v"(b), "v"(c));
    return d;
}
__device__ __forceinline__ f16x2 u2h2(uint32_t v) {
    union { uint32_t u; f16x2 h; } c; c.u = v; return c.h;
}
// LDS-only barrier: skips __syncthreads' implicit vmcnt(0) so in-flight global
// loads (prefetches) and stores survive across the barrier.
__device__ __forceinline__ void barrier_lds() {
    asm volatile("s_waitcnt lgkmcnt(0)\n\ts_barrier" ::: "memory");
}

// ---- K1: fused prep (proven round 17).
__global__ __launch_bounds__(256) void k_prep(
        const float* __restrict__ ce,
        const float* __restrict__ cWih_f, const float* __restrict__ cb_f,
        const float* __restrict__ cWih_b, const float* __restrict__ cb_b,
        const float* __restrict__ wWih_f, const float* __restrict__ wb_f,
        const float* __restrict__ wWih_b, const float* __restrict__ wb_b,
        const float* __restrict__ cWhh_f, const float* __restrict__ cWhh_b,
        const float* __restrict__ W1,
        float* __restrict__ gin, unsigned short* __restrict__ wfrag,
        float* __restrict__ bc, unsigned short* __restrict__ cfrag,
        unsigned short* __restrict__ ffrag) {
    int blk = blockIdx.x, tid = threadIdx.x;
    if (blk < 8) {
        if (tid < 200) {
            int dir = tid / 100, row = tid % 100;
            int g = row / 25, u = row - g*25;
            const float* wih = dir ? cWih_b : cWih_f;
            float bias = dir ? cb_b[row] : cb_f[row];
            int c0 = blk*13, c1 = min(100, c0 + 13);
            for (int c = c0; c < c1; ++c) {
                float s = bias;
#pragma unroll
                for (int k = 0; k < 25; ++k) s += wih[row*25 + k] * ce[c*25 + k];
                gin[(dir*100 + c)*100 + u*4 + g] = s;
            }
        }
    } else if (blk < 258) {
        int idx = (blk - 8)*256 + tid;          // 0..63999
        if (idx < 2*5*25*512) {
            int e  = idx & 7;
            int l  = (idx >> 3) & 63;
            int r  = idx >> 9;
            int nt = r % 25;
            int r2 = r / 25;
            int kc = r2 % 5;
            int d  = r2 / 5;
            int k  = kc*32 + (l >> 4)*8 + e;
            int nl = nt*16 + (l & 15);
            const float* w = d ? wWih_b : wWih_f;
            float v = (k < 150) ? w[nl*150 + k] : 0.f;
            wfrag[idx] = f2bf(v);
        }
        if (idx < 800) {
            int d = idx >= 400 ? 1 : 0, r = idx - d*400;
            bc[idx] = d ? wb_b[r] : wb_f[r];
        }
    } else if (blk < 286) {
        int idx = (blk - 258)*256 + tid;        // 0..7167
        if (idx < 2*7*64*8) {
            int e  = idx & 7;
            int l  = (idx >> 3) & 63;
            int r  = idx >> 9;
            int nt = r % 7;
            int d  = r / 7;
            int k  = (l >> 4)*8 + e;
            int n  = nt*16 + (l & 15);
            const float* w = d ? cWhh_b : cWhh_f;
            float v = (n < 100 && k < 25) ? w[n*25 + k] : 0.f;
            union { f16 h; unsigned short s; } c; c.h = (f16)v;
            cfrag[idx] = c.s;
        }
    } else {
        int idx = (blk - 286)*256 + tid;        // 0..25087
        if (idx < 7*7*512) {
            int e  = idx & 7;
            int l  = (idx >> 3) & 63;
            int r  = idx >> 9;
            int nt = r % 7;
            int kc = r / 7;
            int k  = kc*32 + (l >> 4)*8 + e;
            int n  = nt*16 + (l & 15);
            float v = (n < 100 && k < 200) ? W1[(size_t)n*200 + k] : 0.f;
            ffrag[idx] = f2bf(v);
        }
    }
}

// ---- K2: char BiLSTM on MFMA. v3: 32 words/block, 2048 blocks. LDS 36.4->19 KB
//      doubles co-residency 4->8 blocks/CU (16->32 waves) — A/B probe for the
//      exposed-per-step-latency hypothesis on the 16-step chain. Fragment
//      layouts and slot logic unchanged from the proven 64-word version.
__global__ __launch_bounds__(256)
void k_char(
        const unsigned short* __restrict__ cfrag, const float* __restrict__ gin,
        const int* __restrict__ char_ids, const int* __restrict__ word_num,
        float* __restrict__ wfbuf) {
    __shared__ __align__(16) f16  Hh[32][40];    // h state, row stride 40 (2.5 KB)
    __shared__ __align__(16) float Ct[100][36];  // C^T: [gate*25+u][word] (14.4 KB)
    __shared__ int chlT[16][32];                 // char ids transposed (2 KB)
    int wt = blockIdx.x >> 1, dir = blockIdx.x & 1;
    int mb = wt*32;
    int tid = threadIdx.x;
    int wv = tid >> 6, lane = tid & 63, lm = lane & 15, lg = lane >> 4;
    int nt0 = wv, nt1 = wv + 4;
    const f16* cf = (const f16*)cfrag;
    half8 B0 = *(const half8*)&cf[((dir*7 + nt0)*64 + lane)*8];
    half8 B1 = {};
    if (nt1 < 7) B1 = *(const half8*)&cf[((dir*7 + nt1)*64 + lane)*8];
    if (tid < 128) {
        int w = tid >> 2, j4 = tid & 3;
        int4 v = *(const int4*)&char_ids[(size_t)(mb + w)*16 + j4*4];
        chlT[j4*4+0][w] = v.x; chlT[j4*4+1][w] = v.y;
        chlT[j4*4+2][w] = v.z; chlT[j4*4+3][w] = v.w;
    }
    for (int i = tid; i < 640; i += 256) ((uint32_t*)Hh)[i] = 0;   // h0=0 + pad
    __syncthreads();
    int ua = tid >> 4;            // 0..15
    int ub = ua + 16;             // valid if <25
    bool hasb = (ub < 25);
    int m0 = (tid & 15)*2;        // 2 words per slot
    float csa[2] = {0,0}, csb[2] = {0,0};
    const float* ginD = gin + dir*100*100;
    f32x4 zz = {0.f, 0.f, 0.f, 0.f};
    int t0 = dir ? 15 : 0;
    float4 Ga[2], Gb[2], Na[2], Nb[2];
#pragma unroll
    for (int j = 0; j < 2; ++j) {
        int c = chlT[t0][m0 + j];
        Ga[j] = *(const float4*)&ginD[c*100 + ua*4];
        Gb[j] = hasb ? *(const float4*)&ginD[c*100 + ub*4] : make_float4(0,0,0,0);
    }
#pragma unroll 1
    for (int tt = 0; tt < 16; ++tt) {
        f32x4 a0[2], a1[2];
#pragma unroll
        for (int mf = 0; mf < 2; ++mf) {
            half8 A = *(const half8*)&Hh[mf*16 + lm][lg*8];
            a0[mf] = __builtin_amdgcn_mfma_f32_16x16x32_f16(A, B0, zz, 0, 0, 0);
            a1[mf] = (nt1 < 7)
                ? __builtin_amdgcn_mfma_f32_16x16x32_f16(A, B1, zz, 0, 0, 0) : zz;
        }
#pragma unroll
        for (int mf = 0; mf < 2; ++mf) {
            *(f32x4*)&Ct[nt0*16 + lm][mf*16 + lg*4] = a0[mf];
            if (nt1 < 7 && nt1*16 + lm < 100)
                *(f32x4*)&Ct[nt1*16 + lm][mf*16 + lg*4] = a1[mf];
        }
        if (tt < 15) {
            int tn = dir ? (14 - tt) : (tt + 1);
            int2 cs2 = *(const int2*)&chlT[tn][m0];
            int cj[2] = {cs2.x, cs2.y};
#pragma unroll
            for (int j = 0; j < 2; ++j) {
                Na[j] = *(const float4*)&ginD[cj[j]*100 + ua*4];
                Nb[j] = hasb ? *(const float4*)&ginD[cj[j]*100 + ub*4]
                             : make_float4(0,0,0,0);
            }
        }
        barrier_lds();
        float2 Ra[4], Rb[4];
#pragma unroll
        for (int g = 0; g < 4; ++g) {
            Ra[g] = *(const float2*)&Ct[g*25 + ua][m0];
            if (hasb) Rb[g] = *(const float2*)&Ct[g*25 + ub][m0];
        }
#pragma unroll
        for (int j = 0; j < 2; ++j) {
            float ra0 = j ? Ra[0].y : Ra[0].x, ra1 = j ? Ra[1].y : Ra[1].x;
            float ra2 = j ? Ra[2].y : Ra[2].x, ra3 = j ? Ra[3].y : Ra[3].x;
            float gi = ra0 + Ga[j].x, gf = ra1 + Ga[j].y;
            float gg = ra2 + Ga[j].z, go = ra3 + Ga[j].w;
            csa[j] = sigf(gf)*csa[j] + sigf(gi)*tanhfast(gg);
            float h = sigf(go)*tanhfast(csa[j]);
            Hh[m0 + j][ua] = (f16)h;
            if (tt == 15) {
                int word = mb + m0 + j, bb = word >> 8, ss = word & 255;
                float mk = (ss < word_num[bb]) ? 1.f : 0.f;
                wfbuf[(size_t)word*152 + 100 + dir*25 + ua] = h*mk;
            }
        }
        if (hasb) {
#pragma unroll
            for (int j = 0; j < 2; ++j) {
                float rb0 = j ? Rb[0].y : Rb[0].x, rb1 = j ? Rb[1].y : Rb[1].x;
                float rb2 = j ? Rb[2].y : Rb[2].x, rb3 = j ? Rb[3].y : Rb[3].x;
                float gi = rb0 + Gb[j].x, gf = rb1 + Gb[j].y;
                float gg = rb2 + Gb[j].z, go = rb3 + Gb[j].w;
                csb[j] = sigf(gf)*csb[j] + sigf(gi)*tanhfast(gg);
                float h = sigf(go)*tanhfast(csb[j]);
                Hh[m0 + j][ub] = (f16)h;
                if (tt == 15) {
                    int word = mb + m0 + j, bb = word >> 8, ss = word & 255;
                    float mk = (ss < word_num[bb]) ? 1.f : 0.f;
                    wfbuf[(size_t)word*152 + 100 + dir*25 + ub] = h*mk;
                }
            }
        }
        barrier_lds();
        if (tt < 15) {
#pragma unroll
            for (int j = 0; j < 2; ++j) { Ga[j] = Na[j]; Gb[j] = Nb[j]; }
        }
    }
}

// ---- K3: word input gates GEMM on MFMA, embedding gather fused into A-staging.
__global__ __launch_bounds__(256)
void k_gemm_mfma(
        const float* __restrict__ wfbuf, const float* __restrict__ we,
        const int* __restrict__ wids, const unsigned short* __restrict__ frag,
        const float* __restrict__ bc, __hip_bfloat16* __restrict__ gates) {
    __shared__ __align__(16) unsigned short As[64*168];   // 21504 B
    int mt  = blockIdx.x >> 1, dir = blockIdx.x & 1;
    int m0  = mt * 64;
    int tid = threadIdx.x;
    int wv  = tid >> 6;
    int lane = tid & 63;
    int lm  = lane & 15;
    int lg  = lane >> 4;
    {
        int row = tid >> 2, qc = tid & 3;
        const float* embp = we + (size_t)wids[m0 + row]*100;
        const float* chp  = wfbuf + (size_t)(m0 + row)*152;
        unsigned* dst = (unsigned*)As + row*84 + qc*19;
#pragma unroll
        for (int i = 0; i < 19; ++i) {
            int c = qc*38 + 2*i;     // even; emb/char boundary (100) never straddled
            float2 v;
            if (c < 100)       v = *(const float2*)&embp[c];
            else if (c < 150)  v = *(const float2*)&chp[c];
            else               v = make_float2(0.f, 0.f);
            dst[i] = ((unsigned)f2bf(v.y) << 16) | f2bf(v.x);
        }
        if (qc == 3) {   // zero k-pad cols 152..159
            unsigned* z = (unsigned*)As + row*84 + 76;
            z[0] = 0; z[1] = 0; z[2] = 0; z[3] = 0;
        }
    }
    __syncthreads();
    f32x4 acc[7][4] = {};
    const unsigned short* fb = frag + (size_t)dir*(5*25*512);
#pragma unroll
    for (int kc = 0; kc < 5; ++kc) {
        bf16x8 bfr[7];
#pragma unroll
        for (int j = 0; j < 7; ++j) {
            int nt = wv + 4*j;
            bf16x8 v = {};
            if (nt < 25)
                v = *(const bf16x8*)&fb[((size_t)(kc*25 + nt)*64 + lane)*8];
            bfr[j] = v;
        }
        bf16x8 afr[4];
#pragma unroll
        for (int mf = 0; mf < 4; ++mf)
            afr[mf] = *(const bf16x8*)&As[(mf*16 + lm)*168 + kc*32 + lg*8];
#pragma unroll
        for (int j = 0; j < 7; ++j) {
            int nt = wv + 4*j;
            if (nt < 25) {
#pragma unroll
                for (int mf = 0; mf < 4; ++mf)
                    acc[j][mf] = __builtin_amdgcn_mfma_f32_16x16x32_bf16(
                        afr[mf], bfr[j], acc[j][mf], 0, 0, 0);
            }
        }
    }
#pragma unroll
    for (int j = 0; j < 7; ++j) {
        int nt = wv + 4*j;
        if (nt >= 25) continue;
        int n = nt*16 + lm;
        float bias = bc[dir*400 + n];
        int u = n % 100, g = n / 100;
#pragma unroll
        for (int mf = 0; mf < 4; ++mf) {
#pragma unroll
            for (int r = 0; r < 4; ++r) {
                int m = m0 + mf*16 + lg*4 + r;
                gates[((size_t)dir*TOK + m)*400 + u*4 + g]
                    = __float2bfloat16(acc[j][mf][r] + bias);
            }
        }
    }
}

// ---- K4: word BiLSTM — dot2, 512 threads, waves_per_eu(2,2), 88 VGPR.
//      PERMANENTLY FROZEN at ~200 µs (structural floor; see r10/r13/r14 notes).
__global__ __launch_bounds__(512)
__attribute__((amdgpu_waves_per_eu(2, 2)))
void k_word(
        const __hip_bfloat16* __restrict__ gates,
        const float* __restrict__ whh_f, const float* __restrict__ whh_b,
        __hip_bfloat16* __restrict__ wh) {
    int b = blockIdx.x >> 1, dir = blockIdx.x & 1;
    int tid = threadIdx.x;
    int wv   = tid >> 6;            // wave 0..7
    int lane = tid & 63;
    int q    = lane >> 4;           // k-quarter: contiguous k in [q*26, q*26+26)
    int u    = wv*16 + (lane & 15); // unit 0..127
    bool act = (u < 100);
    const float* whh = dir ? whh_b : whh_f;
    __shared__ __align__(16) uint32_t Hs[2][64];
    for (int i = tid; i < 128; i += 512) ((uint32_t*)Hs)[i] = 0;
    f16x2 W[4][13];
#pragma unroll
    for (int gi = 0; gi < 4; ++gi)
#pragma unroll
        for (int i = 0; i < 13; ++i) {
            int k0 = q*26 + 2*i;
            f16x2 v = {};
            if (act) {
                const float* r = &whh[(size_t)(gi*100 + u)*100];
                if (k0 < 100)     v.x = (f16)r[k0];
                if (k0 + 1 < 100) v.y = (f16)r[k0+1];
            }
            W[gi][i] = v;
        }
    int hq = u / 26, hr = u - hq*26;
    int hwofs = hq*32 + hr;     // ushort index into Hs[buf]
    float cst = 0.f;
    const unsigned short* gp = (const unsigned short*)gates
                             + (size_t)(dir*TOK + b*256)*400;   // [t][u*4+gate]
    __syncthreads();
    int t0 = dir ? 255 : 0;
    ushort4 Gc = *(const ushort4*)(gp + (size_t)t0*400 + (act ? u*4 : 0));
    ushort4 Gn = Gc;
#pragma unroll 1
    for (int tt = 0; tt < 256; ++tt) {
        int t = dir ? (255 - tt) : tt;
        if (tt < 255) {
            int tn = dir ? (t - 1) : (t + 1);
            Gn = *(const ushort4*)(gp + (size_t)tn*400 + (act ? u*4 : 0));
        }
        const uint32_t* hb = Hs[tt & 1] + q*16;
        const uint4* hp4 = (const uint4*)hb;
        uint4 hA = hp4[0], hB = hp4[1], hC = hp4[2];
        uint32_t hD = hb[12];
        uint32_t hw[13] = {hA.x, hA.y, hA.z, hA.w,
                           hB.x, hB.y, hB.z, hB.w,
                           hC.x, hC.y, hC.z, hC.w, hD};
        float a0 = 0.f, a1 = 0.f, a2 = 0.f, a3 = 0.f;
#pragma unroll
        for (int i = 0; i < 13; ++i) {
            f16x2 h2 = u2h2(hw[i]);
            a0 = dot2(W[0][i], h2, a0);
            a1 = dot2(W[1][i], h2, a1);
            a2 = dot2(W[2][i], h2, a2);
            a3 = dot2(W[3][i], h2, a3);
        }
        a0 += __shfl_xor(a0, 16, 64); a0 += __shfl_xor(a0, 32, 64);
        a1 += __shfl_xor(a1, 16, 64); a1 += __shfl_xor(a1, 32, 64);
        a2 += __shfl_xor(a2, 16, 64); a2 += __shfl_xor(a2, 32, 64);
        a3 += __shfl_xor(a3, 16, 64); a3 += __shfl_xor(a3, 32, 64);
        float gI = bf2f(Gc.x) + a0, gF = bf2f(Gc.y) + a1;
        float gG = bf2f(Gc.z) + a2, gO = bf2f(Gc.w) + a3;
        cst = sigf(gF)*cst + sigf(gI)*tanhfast(gG);
        float h = sigf(gO)*tanhfast(cst);
        if (act && q == 0) {
            union { f16 hh; unsigned short us; } cv; cv.hh = (f16)h;
            ((unsigned short*)Hs[(tt + 1) & 1])[hwofs] = cv.us;
            wh[(size_t)(b*256 + t)*200 + dir*100 + u] = __float2bfloat16(h);
        }
        barrier_lds();   // LDS-only: prefetch + wh stores stay in flight
        Gc = Gn;
    }
}

// ---- K5: feats on MFMA (proven round 12); block 0 zeroes d_out for k_crf.
__global__ __launch_bounds__(256) void k_feats(
        const __hip_bfloat16* __restrict__ wh, const unsigned short* __restrict__ frag,
        const float* __restrict__ b1, const float* __restrict__ W2,
        const float* __restrict__ b2, const int* __restrict__ word_num,
        float* __restrict__ feats, float* __restrict__ out) {
    __shared__ __align__(16) char smem[29696];   // As [64][232]bf16 = 29696 B
    unsigned short* As = (unsigned short*)smem;  // row stride 232 bf16 (116 dwords)
    float* mids = (float*)smem;                  // later: [64][108] f32 = 27648 B
    int m0  = blockIdx.x * 64;
    int tid = threadIdx.x;
    if (blockIdx.x == 0 && tid == 0) out[0] = 0.f;
    int wv  = tid >> 6;
    int lane = tid & 63;
    int lm  = lane & 15;
    int lg  = lane >> 4;
    {
        int row = tid >> 2, qc = tid & 3;
        const uint32_t* src = (const uint32_t*)(wh + (size_t)(m0 + row)*200);
        uint32_t* dst = (uint32_t*)As + row*116 + qc*28;
#pragma unroll
        for (int i = 0; i < 28; ++i) {
            int d = qc*28 + i;
            dst[i] = (d < 100) ? src[d] : 0u;
        }
    }
    __syncthreads();
    f32x4 acc[2][4] = {};
#pragma unroll
    for (int kc = 0; kc < 7; ++kc) {
        bf16x8 bfr[2];
#pragma unroll
        for (int j = 0; j < 2; ++j) {
            int nt = wv + 4*j;
            bf16x8 v = {};
            if (nt < 7)
                v = *(const bf16x8*)&frag[((size_t)(kc*7 + nt)*64 + lane)*8];
            bfr[j] = v;
        }
        bf16x8 afr[4];
#pragma unroll
        for (int mf = 0; mf < 4; ++mf)
            afr[mf] = *(const bf16x8*)&As[(mf*16 + lm)*232 + kc*32 + lg*8];
#pragma unroll
        for (int j = 0; j < 2; ++j) {
            int nt = wv + 4*j;
            if (nt < 7) {
#pragma unroll
                for (int mf = 0; mf < 4; ++mf)
                    acc[j][mf] = __builtin_amdgcn_mfma_f32_16x16x32_bf16(
                        afr[mf], bfr[j], acc[j][mf], 0, 0, 0);
            }
        }
    }
    __syncthreads();   // As dead; smem becomes mids
#pragma unroll
    for (int j = 0; j < 2; ++j) {
        int nt = wv + 4*j;
        if (nt >= 7) continue;
        int n = nt*16 + lm;
        if (n >= 100) continue;
        float b1v = b1[n];
#pragma unroll
        for (int mf = 0; mf < 4; ++mf) {
#pragma unroll
            for (int r = 0; r < 4; ++r)
                mids[(mf*16 + lg*4 + r)*108 + n] = tanhfast(acc[j][mf][r] + b1v);
        }
    }
    __syncthreads();
    for (int idx = tid; idx < 576; idx += 256) {
        int tok = idx / 9, lab = idx - tok*9;
        int m = m0 + tok, bb = m >> 8, s = m & 255;
        float v = b2[lab];
        const f32x4* mp = (const f32x4*)&mids[tok*108];
        const float4* wp = (const float4*)(W2 + lab*100);
#pragma unroll
        for (int k = 0; k < 25; ++k) {
            f32x4 mv = mp[k];
            float4 wv4 = wp[k];
            v += mv[0]*wv4.x + mv[1]*wv4.y + mv[2]*wv4.z + mv[3]*wv4.w;
        }
        feats[(size_t)m*12 + lab] = (s < word_num[bb]) ? v : 0.f;
    }
}

// ---- K6: CRF (obs prefetch + tree reductions + atomic reduce, proven r16/r17).
__global__ __launch_bounds__(64) void k_crf(
        const float* __restrict__ feats, const float* __restrict__ T,
        const int* __restrict__ word_num, const int* __restrict__ label_ids,
        float* __restrict__ out) {
    int b = blockIdx.x, lane = threadIdx.x;
    int n = word_num[b];
    const int*   lab = label_ids + b*256;
    const float* fb  = feats + (size_t)b*256*12;
    float nm = 0.f;
    for (int t = lane; t < n; t += 64) {
        int lt = lab[t];
        int lp = (t == 0) ? 9 : lab[t-1];
        nm += fb[t*12 + lt] + T[lp*11 + lt];
    }
#pragma unroll
    for (int o = 32; o > 0; o >>= 1) nm += __shfl_down(nm, o, 64);
    nm = __shfl(nm, 0, 64);
    nm += T[lab[n-1]*11 + 10];
    int j = lane;
    float Tc[11];
#pragma unroll
    for (int i = 0; i < 11; ++i) Tc[i] = T[i*11 + (j < 11 ? j : 0)];
    float alpha = (j == 9) ? 0.f : -1000.f;
    float obs = (j < 9) ? fb[j] : -1000.f;      // t = 0 (n >= 1 guaranteed)
    for (int t = 0; t < n; ++t) {
        float obs_n = -1000.f;
        if (t + 1 < n && j < 9) obs_n = fb[(t+1)*12 + j];
        float v[11];
#pragma unroll
        for (int i = 0; i < 11; ++i) v[i] = __shfl(alpha, i, 64) + Tc[i];
        float m01 = fmaxf(v[0], v[1]), m23 = fmaxf(v[2], v[3]);
        float m45 = fmaxf(v[4], v[5]), m67 = fmaxf(v[6], v[7]);
        float m89 = fmaxf(v[8], v[9]);
        float mA = fmaxf(m01, m23), mB = fmaxf(m45, m67), mC = fmaxf(m89, v[10]);
        float mx = fmaxf(fmaxf(mA, mB), mC);
        float e0 = __expf(v[0]-mx), e1 = __expf(v[1]-mx), e2 = __expf(v[2]-mx);
        float e3 = __expf(v[3]-mx), e4 = __expf(v[4]-mx), e5 = __expf(v[5]-mx);
        float e6 = __expf(v[6]-mx), e7 = __expf(v[7]-mx), e8 = __expf(v[8]-mx);
        float e9 = __expf(v[9]-mx), e10 = __expf(v[10]-mx);
        float s01 = e0+e1, s23 = e2+e3, s45 = e4+e5, s67 = e6+e7, s89 = e8+e9;
        float sA = s01+s23, sB = s45+s67, sC = s89+e10;
        float ssum = (sA+sB) + sC;
        alpha = obs + mx + __logf(ssum);
        obs = obs_n;
    }
    float vv[11];
#pragma unroll
    for (int i = 0; i < 11; ++i) vv[i] = __shfl(alpha, i, 64) + Tc[i];
    float m01 = fmaxf(vv[0], vv[1]), m23 = fmaxf(vv[2], vv[3]);
    float m45 = fmaxf(vv[4], vv[5]), m67 = fmaxf(vv[6], vv[7]);
    float m89 = fmaxf(vv[8], vv[9]);
    float mx = fmaxf(fmaxf(fmaxf(m01, m23), fmaxf(m45, m67)), fmaxf(m89, vv[10]));
    float ssum = 0.f;
#pragma unroll
    for (int i = 0; i < 11; ++i) ssum += __expf(vv[i] - mx);
    float denom = __shfl(mx + __logf(ssum), 10, 64);
    if (lane == 0) atomicAdd(out, (denom - nm) * (1.0f/128.0f));
}

extern "C" void kernel_launch(void* const* d_in, const int* in_sizes, int n_in,
                              void* d_out, int out_size, void* d_ws, size_t ws_size,
                              hipStream_t stream) {
    const float* word_emb = (const float*)d_in[0];
    const float* char_emb = (const float*)d_in[1];
    const float* cWih_f   = (const float*)d_in[2];
    const float* cWhh_f   = (const float*)d_in[3];
    const float* cb_f     = (const float*)d_in[4];
    const float* cWih_b   = (const float*)d_in[5];
    const float* cWhh_b   = (const float*)d_in[6];
    const float* cb_b     = (const float*)d_in[7];
    const float* wWih_f   = (const float*)d_in[8];
    const float* wWhh_f   = (const float*)d_in[9];
    const float* wb_f     = (const float*)d_in[10];
    const float* wWih_b   = (const float*)d_in[11];
    const float* wWhh_b   = (const float*)d_in[12];
    const float* wb_b     = (const float*)d_in[13];
    const float* W1       = (const float*)d_in[14];
    const float* b1       = (const float*)d_in[15];
    const float* W2       = (const float*)d_in[16];
    const float* b2       = (const float*)d_in[17];
    const float* T        = (const float*)d_in[18];
    const int* word_num   = (const int*)d_in[19];
    const int* word_ids   = (const int*)d_in[20];
    const int* char_ids   = (const int*)d_in[21];
    const int* label_ids  = (const int*)d_in[22];

    char* ws = (char*)d_ws;
    float* gin            = (float*)(ws);                       //    80,000 B
    unsigned short* ffrag = (unsigned short*)(ws + 80000);      //    50,176 B
    float* bc             = (float*)(ws + 566400);              //     3,200 B
    float* wfbuf          = (float*)(ws + 569600);              // 19,922,944 B [32768][152] (cols 100..149 used)
    __hip_bfloat16* gates = (__hip_bfloat16*)(ws + 20492544);   // 52,428,800 B [2][32768][400]
    __hip_bfloat16* wh    = (__hip_bfloat16*)(ws + 72921344);   // 13,107,200 B [32768][200]
    float* feats          = (float*)(ws + 86028544);            //  1,572,864 B [32768][12]
    // cfrag (14,336 B) aliases head of `gates`: k_prep -> k_char reads ->
    // overwritten by k_gemm_mfma (strictly serial).
    unsigned short* cfrag = (unsigned short*)(ws + 20492544);
    // wfrag (256,000 B) aliases head of `wh`: k_prep -> k_gemm_mfma -> k_word
    // overwrites wh (serial).
    unsigned short* wfrag = (unsigned short*)(ws + 72921344);

    k_prep  <<<384, 256, 0, stream>>>(char_emb, cWih_f, cb_f, cWih_b, cb_b,
                                      wWih_f, wb_f, wWih_b, wb_b,
                                      cWhh_f, cWhh_b, W1,
                                      gin, wfrag, bc, cfrag, ffrag);
    k_char  <<<2048, 256, 0, stream>>>(cfrag, gin, char_ids, word_num, wfbuf);
    k_gemm_mfma<<<1024, 256, 0, stream>>>(wfbuf, word_emb, word_ids, wfrag, bc, gates);
    k_word  <<<256, 512, 0, stream>>>(gates, wWhh_f, wWhh_b, wh);
    k_feats <<<512, 256, 0, stream>>>(wh, ffrag, b1, W2, b2, word_num, feats, (float*)d_out);
    k_crf   <<<128, 64, 0, stream>>>(feats, T, word_num, label_ids, (float*)d_out);
}